// Round 7
// baseline (410.784 us; speedup 1.0000x reference)
//
#include <hip/hip_runtime.h>
#include <hip/hip_bf16.h>

#define N_NODES 100000
#define N_EDGES 1600000
#define IN_DIM 128
#define HID_DIM 128
#define OUT_DIM 40

#define BSHIFT 9                 // 512 nodes per bucket
#define NBUCK 196                // ceil(100000/512)
#define CHUNK 4096               // edges per scatter/count block
#define NCHUNK ((N_EDGES + CHUNK - 1) / CHUNK)

typedef __attribute__((ext_vector_type(8))) short short8;   // 8 x bf16 (4 VGPRs)
typedef __attribute__((ext_vector_type(4))) float float4v;  // MFMA C/D + float4 loads
typedef __attribute__((ext_vector_type(2))) unsigned int u32x2;

typedef unsigned short u16;
typedef unsigned int u32;
typedef unsigned long long u64;

__device__ __forceinline__ float bflo(u32 v) { union { u32 u; float f; } c; c.u = v << 16; return c.f; }
__device__ __forceinline__ float bfhi(u32 v) { union { u32 u; float f; } c; c.u = v & 0xffff0000u; return c.f; }
__device__ __forceinline__ u16 f2bf(float f) {  // RNE
    union { float f; u32 u; } c; c.f = f;
    u32 r = c.u + 0x7fffu + ((c.u >> 16) & 1u);
    return (u16)(r >> 16);
}

// ---- fused: f32->bf16 conversions + bucket histogram ------------------------
// blocks [0, XBLKS): convert x
// blocks [XBLKS, XBLKS+44): convert 4 weight mats (W2 zero-padded to 48 rows)
// blocks [XBLKS+44, XBLKS+44+NCHUNK): dst-bucket histogram

#define XBLKS ((N_NODES * IN_DIM / 4 + 255) / 256)

__global__ __launch_bounds__(256) void k_cvtall(
    const float* __restrict__ x, u16* __restrict__ xb,
    const float* __restrict__ w1l, const float* __restrict__ w1r,
    const float* __restrict__ w2l, const float* __restrict__ w2r,
    u16* __restrict__ w1lb, u16* __restrict__ w1rb,
    u16* __restrict__ w2lb, u16* __restrict__ w2rb,
    const int* __restrict__ idx, int* __restrict__ bucket_size) {
    __shared__ int cnt[NBUCK];
    int b = blockIdx.x;
    if (b < XBLKS) {
        int i = b * 256 + threadIdx.x;
        if (i < N_NODES * IN_DIM / 4) {
            float4v v = reinterpret_cast<const float4v*>(x)[i];
            u32x2 o;
            o.x = ((u32)f2bf(v.y) << 16) | (u32)f2bf(v.x);
            o.y = ((u32)f2bf(v.w) << 16) | (u32)f2bf(v.z);
            reinterpret_cast<u32x2*>(xb)[i] = o;
        }
        return;
    }
    if (b < XBLKS + 44) {
        int i = (b - XBLKS) * 256 + threadIdx.x;   // granule = 4 elems
        const int G1 = HID_DIM * IN_DIM / 4;       // 4096
        const int G2 = 48 * 128 / 4;               // 1536
        const int REAL2 = OUT_DIM * 128 / 4;       // 1280
        const float* s; u16* d; int j; int real;
        if (i < G1)               { s = w1l; d = w1lb; j = i;            real = G1; }
        else if (i < 2*G1)        { s = w1r; d = w1rb; j = i - G1;       real = G1; }
        else if (i < 2*G1+G2)     { s = w2l; d = w2lb; j = i - 2*G1;     real = REAL2; }
        else if (i < 2*G1+2*G2)   { s = w2r; d = w2rb; j = i - 2*G1-G2;  real = REAL2; }
        else return;
        u32x2 o;
        if (j < real) {
            float4v v = reinterpret_cast<const float4v*>(s)[j];
            o.x = ((u32)f2bf(v.y) << 16) | (u32)f2bf(v.x);
            o.y = ((u32)f2bf(v.w) << 16) | (u32)f2bf(v.z);
        } else { o.x = 0; o.y = 0; }
        reinterpret_cast<u32x2*>(d)[j] = o;
        return;
    }
    // histogram part
    int t = threadIdx.x;
    for (int i = t; i < NBUCK; i += 256) cnt[i] = 0;
    __syncthreads();
    int base = (b - XBLKS - 44) * CHUNK;
    int n = min(CHUNK, N_EDGES - base);
    for (int i = t; i < n; i += 256)
        atomicAdd(&cnt[idx[N_EDGES + base + i] >> BSHIFT], 1);
    __syncthreads();
    for (int i = t; i < NBUCK; i += 256)
        if (cnt[i]) atomicAdd(&bucket_size[i], cnt[i]);
}

// ---- CSR build: radix partition by dst bucket -------------------------------

__global__ __launch_bounds__(256) void k_bscan(const int* __restrict__ bucket_size,
                                               int* __restrict__ bucket_base,
                                               int* __restrict__ bucket_cur) {
    __shared__ int sa[256], sb[256];
    int t = threadIdx.x;
    int v = (t < NBUCK) ? bucket_size[t] : 0;
    sa[t] = v;
    __syncthreads();
    int *s = sa, *d = sb;
    for (int dd = 1; dd < 256; dd <<= 1) {
        d[t] = s[t] + ((t >= dd) ? s[t - dd] : 0);
        __syncthreads();
        int* tm = s; s = d; d = tm;
    }
    if (t < NBUCK) {
        int base = s[t] - v;   // exclusive prefix
        bucket_base[t] = base;
        bucket_cur[t] = base;
    }
}

__global__ __launch_bounds__(1024) void k_bscatter(const int* __restrict__ idx,
                                                   int* __restrict__ bucket_cur,
                                                   u64* __restrict__ rec) {
    __shared__ int cnt[NBUCK], lofs[NBUCK], gbase[NBUCK], cnt2[NBUCK];
    __shared__ int sa[256], sb[256];
    __shared__ u64 lrec[CHUNK];
    int t = threadIdx.x;
    int nt = blockDim.x;
    for (int i = t; i < NBUCK; i += nt) { cnt[i] = 0; cnt2[i] = 0; }
    __syncthreads();
    int base = blockIdx.x * CHUNK;
    int n = min(CHUNK, N_EDGES - base);
    for (int i = t; i < n; i += nt)
        atomicAdd(&cnt[idx[N_EDGES + base + i] >> BSHIFT], 1);
    __syncthreads();
    if (t < 256) {
        int v = (t < NBUCK) ? cnt[t] : 0;
        sa[t] = v;
    }
    __syncthreads();
    int *s = sa, *d = sb;
    for (int dd = 1; dd < 256; dd <<= 1) {
        if (t < 256) d[t] = s[t] + ((t >= dd) ? s[t - dd] : 0);
        __syncthreads();
        int* tm = s; s = d; d = tm;
    }
    if (t < NBUCK) {
        int v = cnt[t];
        lofs[t] = s[t] - v;
        gbase[t] = v ? atomicAdd(&bucket_cur[t], v) : 0;
    }
    __syncthreads();
    for (int i = t; i < n; i += nt) {
        int srcv = idx[base + i];
        int dstv = idx[N_EDGES + base + i];
        int b = dstv >> BSHIFT;
        int p = lofs[b] + atomicAdd(&cnt2[b], 1);
        lrec[p] = ((u64)(u32)dstv << 32) | (u32)srcv;
    }
    __syncthreads();
    for (int i = t; i < n; i += nt) {
        u64 r = lrec[i];
        int b = ((int)(r >> 32)) >> BSHIFT;
        __builtin_nontemporal_store(r, &rec[gbase[b] + (i - lofs[b])]);
    }
}

// row_start is N_NODES+1 entries; row_end[n] == row_start[n+1] by construction
// (csr is globally contiguous: bucket bases from the scan, rows contiguous
// within buckets, bucket end == next bucket base).
__global__ __launch_bounds__(1024) void k_bfill(const u64* __restrict__ rec,
                                                const int* __restrict__ bucket_base,
                                                const int* __restrict__ bucket_size,
                                                int* __restrict__ row_start,
                                                int* __restrict__ csr) {
    __shared__ int deg[512], cur[512];
    __shared__ int sa[512], sb[512];
    int t = threadIdx.x;
    int nt = blockDim.x;
    int b = blockIdx.x;
    int node0 = b << BSHIFT;
    int nn = min(512, N_NODES - node0);
    int ebase = bucket_base[b];
    int esz = bucket_size[b];
    for (int i = t; i < 512; i += nt) deg[i] = 0;
    __syncthreads();
    for (int i = t; i < esz; i += nt)
        atomicAdd(&deg[((int)(rec[ebase + i] >> 32)) & 511], 1);
    __syncthreads();
    for (int i = t; i < 512; i += nt) sa[i] = deg[i];
    __syncthreads();
    int *s = sa, *d = sb;
    for (int dd = 1; dd < 512; dd <<= 1) {
        for (int i = t; i < 512; i += nt) d[i] = s[i] + ((i >= dd) ? s[i - dd] : 0);
        __syncthreads();
        int* tm = s; s = d; d = tm;
    }
    for (int i = t; i < 512; i += nt) {
        int excl = s[i] - deg[i];
        cur[i] = excl;
        if (i < nn) row_start[node0 + i] = ebase + excl;
    }
    if (b == NBUCK - 1 && t == 0) row_start[N_NODES] = N_EDGES;
    __syncthreads();
    for (int i = t; i < esz; i += nt) {
        u64 r = rec[ebase + i];
        int dl = ((int)(r >> 32)) & 511;
        int p = atomicAdd(&cur[dl], 1);
        __builtin_nontemporal_store((int)(r & 0xffffffffu), &csr[ebase + p]);
    }
}

// ---- Mean aggregation: one wave per dst node --------------------------------
// Edge-paired gathers: lanes split 32/32, 8B/lane => one instr fetches 512B
// spanning two source rows. 8 edges/iter (4 gathers, 2 KB in flight); index
// loads software-pipelined one iteration ahead. (16-edge unroll regressed:
// mean degree = 16 => half the edges fell into the tail loop.)

__global__ void k_agg(const u16* __restrict__ feat,
                      const int* __restrict__ csr,
                      const int* __restrict__ row_start,
                      u16* __restrict__ agg) {
    int n = blockIdx.x * 4 + (threadIdx.x >> 6);
    int lane = threadIdx.x & 63;
    if (n >= N_NODES) return;
    int s = row_start[n];
    int e = row_start[n + 1];
    int half = lane >> 5;     // which edge of the pair
    int li = lane & 31;       // 8B chunk within row (dims 4li..4li+3)
    const u32x2* fp = reinterpret_cast<const u32x2*>(feat);   // 32 granules/row
    float a0 = 0.f, a1 = 0.f, a2 = 0.f, a3 = 0.f;
    int p = s;
    int i0 = 0, i1 = 0, i2 = 0, i3 = 0;
    if (p + 8 <= e) {
        i0 = csr[p + half];     i1 = csr[p + 2 + half];
        i2 = csr[p + 4 + half]; i3 = csr[p + 6 + half];
    }
    while (p + 8 <= e) {
        u32x2 v0 = fp[i0 * 32 + li];
        u32x2 v1 = fp[i1 * 32 + li];
        u32x2 v2 = fp[i2 * 32 + li];
        u32x2 v3 = fp[i3 * 32 + li];
        p += 8;
        if (p + 8 <= e) {       // prefetch next indices during gather latency
            i0 = csr[p + half];     i1 = csr[p + 2 + half];
            i2 = csr[p + 4 + half]; i3 = csr[p + 6 + half];
        }
        a0 += bflo(v0.x) + bflo(v1.x) + bflo(v2.x) + bflo(v3.x);
        a1 += bfhi(v0.x) + bfhi(v1.x) + bfhi(v2.x) + bfhi(v3.x);
        a2 += bflo(v0.y) + bflo(v1.y) + bflo(v2.y) + bflo(v3.y);
        a3 += bfhi(v0.y) + bfhi(v1.y) + bfhi(v2.y) + bfhi(v3.y);
    }
    for (; p + 2 <= e; p += 2) {
        int i = csr[p + half];
        u32x2 v = fp[i * 32 + li];
        a0 += bflo(v.x); a1 += bfhi(v.x);
        a2 += bflo(v.y); a3 += bfhi(v.y);
    }
    if (p < e && half == 0) {   // single leftover edge: lo-half lanes only
        int i = csr[p];
        u32x2 v = fp[i * 32 + li];
        a0 += bflo(v.x); a1 += bfhi(v.x);
        a2 += bflo(v.y); a3 += bfhi(v.y);
    }
    // fold the two halves
    a0 += __shfl_xor(a0, 32);
    a1 += __shfl_xor(a1, 32);
    a2 += __shfl_xor(a2, 32);
    a3 += __shfl_xor(a3, 32);
    if (half == 0) {
        float sc = 1.0f / (float)max(e - s, 1);
        u32x2 o;
        o.x = ((u32)f2bf(a1 * sc) << 16) | (u32)f2bf(a0 * sc);
        o.y = ((u32)f2bf(a3 * sc) << 16) | (u32)f2bf(a2 * sc);
        __builtin_nontemporal_store(o, &reinterpret_cast<u32x2*>(agg)[n * 32 + li]);
    }
}

// ---- Dense layer 1: h = relu(normalize(agg@W1l^T + b1 + x@W1r^T)) ----------
// MFMA 16x16x32 bf16. One wave = 16 nodes x 128 outs, K=256 (agg half, x half).
// D: col(o)=lane&15, row(node)=quad*4+reg.

__global__ __launch_bounds__(256) void k_dense1(
    const u16* __restrict__ agg, const u16* __restrict__ x,
    const u16* __restrict__ W1l, const u16* __restrict__ W1r,
    const float* __restrict__ b1, u16* __restrict__ h) {
    int wave = threadIdx.x >> 6;
    int lane = threadIdx.x & 63;
    int nb = blockIdx.x * 64 + wave * 16;
    int q = lane >> 4;
    int m = lane & 15;
    int arow = nb + m;
    if (arow >= N_NODES) arow = N_NODES - 1;   // clamp loads; stores are guarded

    float4v acc[8];
    #pragma unroll
    for (int ct = 0; ct < 8; ++ct) acc[ct] = (float4v){0.f, 0.f, 0.f, 0.f};

    const u16* Ap[2] = { agg, x };
    const u16* Bp[2] = { W1l, W1r };
    #pragma unroll
    for (int half = 0; half < 2; ++half) {
        const u16* A = Ap[half];
        const u16* B = Bp[half];
        #pragma unroll
        for (int ks = 0; ks < 4; ++ks) {
            int k0 = ks * 32 + q * 8;
            short8 a = *reinterpret_cast<const short8*>(A + arow * 128 + k0);
            #pragma unroll
            for (int ct = 0; ct < 8; ++ct) {
                short8 b = *reinterpret_cast<const short8*>(B + (ct * 16 + m) * 128 + k0);
                acc[ct] = __builtin_amdgcn_mfma_f32_16x16x32_bf16(a, b, acc[ct], 0, 0, 0);
            }
        }
    }

    float bias[8];
    #pragma unroll
    for (int ct = 0; ct < 8; ++ct) bias[ct] = b1[ct * 16 + m];

    float nsq[4] = { 0.f, 0.f, 0.f, 0.f };
    #pragma unroll
    for (int ct = 0; ct < 8; ++ct)
        #pragma unroll
        for (int r = 0; r < 4; ++r) {
            float v = acc[ct][r] + bias[ct];
            acc[ct][r] = v;
            nsq[r] += v * v;
        }
    #pragma unroll
    for (int r = 0; r < 4; ++r) {
        float t = nsq[r];
        t += __shfl_xor(t, 1);
        t += __shfl_xor(t, 2);
        t += __shfl_xor(t, 4);
        t += __shfl_xor(t, 8);
        nsq[r] = 1.0f / fmaxf(sqrtf(t), 1e-12f);
    }
    #pragma unroll
    for (int r = 0; r < 4; ++r) {
        int node = nb + q * 4 + r;
        if (node < N_NODES) {
            #pragma unroll
            for (int ct = 0; ct < 8; ++ct) {
                float v = fmaxf(acc[ct][r] * nsq[r], 0.0f);
                h[node * 128 + ct * 16 + m] = f2bf(v);
            }
        }
    }
}

// ---- Dense layer 2 + log_softmax, MFMA version ------------------------------
// One wave = 16 nodes x 48 cols (3 ct tiles; cols 40..47 zero-padded weights).

__global__ __launch_bounds__(256) void k_dense2(
    const u16* __restrict__ agg, const u16* __restrict__ hfeat,
    const u16* __restrict__ W2lb, const u16* __restrict__ W2rb,
    const float* __restrict__ b2, float* __restrict__ out) {
    int wave = threadIdx.x >> 6;
    int lane = threadIdx.x & 63;
    int nb = blockIdx.x * 64 + wave * 16;
    int q = lane >> 4;
    int m = lane & 15;
    int arow = nb + m;
    if (arow >= N_NODES) arow = N_NODES - 1;

    float4v acc[3];
    #pragma unroll
    for (int ct = 0; ct < 3; ++ct) acc[ct] = (float4v){0.f, 0.f, 0.f, 0.f};

    const u16* Ap[2] = { agg, hfeat };
    const u16* Bp[2] = { W2lb, W2rb };
    #pragma unroll
    for (int half = 0; half < 2; ++half) {
        const u16* A = Ap[half];
        const u16* B = Bp[half];
        #pragma unroll
        for (int ks = 0; ks < 4; ++ks) {
            int k0 = ks * 32 + q * 8;
            short8 a = *reinterpret_cast<const short8*>(A + arow * 128 + k0);
            #pragma unroll
            for (int ct = 0; ct < 3; ++ct) {
                short8 b = *reinterpret_cast<const short8*>(B + (ct * 16 + m) * 128 + k0);
                acc[ct] = __builtin_amdgcn_mfma_f32_16x16x32_bf16(a, b, acc[ct], 0, 0, 0);
            }
        }
    }

    float bias[3];
    #pragma unroll
    for (int ct = 0; ct < 3; ++ct) {
        int row = ct * 16 + m;
        bias[ct] = (row < OUT_DIM) ? b2[row] : 0.0f;
    }

    float nsq[4] = { 0.f, 0.f, 0.f, 0.f };
    #pragma unroll
    for (int ct = 0; ct < 3; ++ct)
        #pragma unroll
        for (int r = 0; r < 4; ++r) {
            float v = acc[ct][r] + bias[ct];
            acc[ct][r] = v;
            nsq[r] += v * v;
        }
    #pragma unroll
    for (int r = 0; r < 4; ++r) {
        float t = nsq[r];
        t += __shfl_xor(t, 1);
        t += __shfl_xor(t, 2);
        t += __shfl_xor(t, 4);
        t += __shfl_xor(t, 8);
        nsq[r] = 1.0f / fmaxf(sqrtf(t), 1e-12f);
    }

    float mv[4] = { 0.f, 0.f, 0.f, 0.f };
    #pragma unroll
    for (int ct = 0; ct < 3; ++ct)
        #pragma unroll
        for (int r = 0; r < 4; ++r) {
            float v = fmaxf(acc[ct][r] * nsq[r], 0.0f);
            acc[ct][r] = v;
            mv[r] = fmaxf(mv[r], v);
        }
    #pragma unroll
    for (int r = 0; r < 4; ++r) {
        float t = mv[r];
        t = fmaxf(t, __shfl_xor(t, 1));
        t = fmaxf(t, __shfl_xor(t, 2));
        t = fmaxf(t, __shfl_xor(t, 4));
        t = fmaxf(t, __shfl_xor(t, 8));
        mv[r] = t;
    }

    float se[4] = { 0.f, 0.f, 0.f, 0.f };
    #pragma unroll
    for (int ct = 0; ct < 3; ++ct) {
        bool valid = (ct < 2) || (m < 8);
        #pragma unroll
        for (int r = 0; r < 4; ++r)
            se[r] += valid ? __expf(acc[ct][r] - mv[r]) : 0.0f;
    }
    #pragma unroll
    for (int r = 0; r < 4; ++r) {
        float t = se[r];
        t += __shfl_xor(t, 1);
        t += __shfl_xor(t, 2);
        t += __shfl_xor(t, 4);
        t += __shfl_xor(t, 8);
        se[r] = __logf(t);
    }

    #pragma unroll
    for (int r = 0; r < 4; ++r) {
        int node = nb + q * 4 + r;
        if (node < N_NODES) {
            #pragma unroll
            for (int ct = 0; ct < 3; ++ct) {
                int col = ct * 16 + m;
                if (col < OUT_DIM)
                    out[node * OUT_DIM + col] = acc[ct][r] - mv[r] - se[r];
            }
        }
    }
}

// ---- launch -----------------------------------------------------------------

extern "C" void kernel_launch(void* const* d_in, const int* in_sizes, int n_in,
                              void* d_out, int out_size, void* d_ws, size_t ws_size,
                              hipStream_t stream) {
    const float* x   = (const float*)d_in[0];
    const int*   idx = (const int*)d_in[1];
    const float* W1l = (const float*)d_in[2];
    const float* b1  = (const float*)d_in[3];
    const float* W1r = (const float*)d_in[4];
    const float* W2l = (const float*)d_in[5];
    const float* b2  = (const float*)d_in[6];
    const float* W2r = (const float*)d_in[7];
    float* out = (float*)d_out;

    char* ws = (char*)d_ws;
    int*   bucket_size = (int*)(ws + 0);        // 784 B (memset 0)
    int*   bucket_base = (int*)(ws + 4096);     // 784 B
    int*   bucket_cur  = (int*)(ws + 8192);     // 784 B
    int*   row_start   = (int*)(ws + 16384);    // (N+1)*4 B
    int*   csr         = (int*)(ws + 1216384);  // 6.4 MB -> ends 7616384
    u16*   xb          = (u16*)(ws + 7616512);  // 25.6 MB bf16(x)
    u16*   agg         = (u16*)(ws + 33216512); // 25.6 MB
    u16*   h           = (u16*)(ws + 58816512); // 25.6 MB
    u64*   rec         = (u64*)(ws + 58816512); // 12.8 MB, ALIASES h (disjoint lifetime)
    u16*   W1lb        = (u16*)(ws + 84416512); // 32768 B
    u16*   W1rb        = (u16*)(ws + 84449280); // 32768 B
    u16*   W2lb        = (u16*)(ws + 84482048); // 12288 B (48x128 padded)
    u16*   W2rb        = (u16*)(ws + 84494336); // 12288 B

    hipMemsetAsync(bucket_size, 0, NBUCK * sizeof(int), stream);

    // conversions + bucket histogram, one launch
    k_cvtall<<<XBLKS + 44 + NCHUNK, 256, 0, stream>>>(
        x, xb, W1l, W1r, W2l, W2r, W1lb, W1rb, W2lb, W2rb, idx, bucket_size);

    // CSR build via radix partition
    k_bscan<<<1, 256, 0, stream>>>(bucket_size, bucket_base, bucket_cur);
    k_bscatter<<<NCHUNK, 1024, 0, stream>>>(idx, bucket_cur, rec);
    k_bfill<<<NBUCK, 1024, 0, stream>>>(rec, bucket_base, bucket_size,
                                        row_start, csr);

    // layer 1
    k_agg<<<N_NODES / 4, 256, 0, stream>>>(xb, csr, row_start, agg);
    k_dense1<<<(N_NODES + 63) / 64, 256, 0, stream>>>(agg, xb, W1lb, W1rb, b1, h);
    // layer 2
    k_agg<<<N_NODES / 4, 256, 0, stream>>>(h, csr, row_start, agg);
    k_dense2<<<(N_NODES + 63) / 64, 256, 0, stream>>>(agg, h, W2lb, W2rb, b2, out);
}

// Round 8
// 312.036 us; speedup vs baseline: 1.3165x; 1.3165x over previous
//
#include <hip/hip_runtime.h>
#include <hip/hip_bf16.h>

#define N_NODES 100000
#define N_EDGES 1600000
#define IN_DIM 128
#define HID_DIM 128
#define OUT_DIM 40

#define BSHIFT 9                 // 512 nodes per bucket
#define NBUCK 196                // ceil(100000/512)
#define CHUNK 4096               // edges per scatter/count block
#define NCHUNK ((N_EDGES + CHUNK - 1) / CHUNK)

typedef __attribute__((ext_vector_type(8))) short short8;   // 8 x bf16 (4 VGPRs)
typedef __attribute__((ext_vector_type(4))) float float4v;  // MFMA C/D + float4 loads
typedef __attribute__((ext_vector_type(2))) unsigned int u32x2;
typedef __attribute__((ext_vector_type(4))) unsigned int u32x4;

typedef unsigned short u16;
typedef unsigned int u32;
typedef unsigned long long u64;

__device__ __forceinline__ float bflo(u32 v) { union { u32 u; float f; } c; c.u = v << 16; return c.f; }
__device__ __forceinline__ float bfhi(u32 v) { union { u32 u; float f; } c; c.u = v & 0xffff0000u; return c.f; }
__device__ __forceinline__ u16 f2bf(float f) {  // RNE
    union { float f; u32 u; } c; c.f = f;
    u32 r = c.u + 0x7fffu + ((c.u >> 16) & 1u);
    return (u16)(r >> 16);
}
__device__ __forceinline__ u32 pk(float lo, float hi) {
    return ((u32)f2bf(hi) << 16) | (u32)f2bf(lo);
}

// ---- fused: x convert + W swizzle-convert + bucket histogram ----------------
// W matrices are converted to MFMA-fragment-linear layout:
//   frag id t = (ct*4+ks)*64 + lane ; element j in [0,8)
//   src: row = ct*16 + (lane&15), col = ks*32 + (lane>>4)*8 + j
//   dst u16 index = t*8 + j  (so a wave's B-frag load = 1 KB contiguous)

#define XBLKS ((N_NODES * IN_DIM / 4 + 255) / 256)
#define WTRIP1 2048              // 8ct*4ks*64lane per W1 matrix
#define WTRIP2 768               // 3ct*4ks*64lane per W2 matrix (48 padded rows)
#define WBLKS 22                 // ceil((2*2048+2*768)/256)

__global__ __launch_bounds__(256) void k_cvtall(
    const float* __restrict__ x, u16* __restrict__ xb,
    const float* __restrict__ w1l, const float* __restrict__ w1r,
    const float* __restrict__ w2l, const float* __restrict__ w2r,
    u16* __restrict__ w1lf, u16* __restrict__ w1rf,
    u16* __restrict__ w2lf, u16* __restrict__ w2rf,
    const int* __restrict__ idx, int* __restrict__ bucket_size) {
    __shared__ int cnt[NBUCK];
    int b = blockIdx.x;
    if (b < XBLKS) {
        int i = b * 256 + threadIdx.x;
        if (i < N_NODES * IN_DIM / 4) {
            float4v v = reinterpret_cast<const float4v*>(x)[i];
            u32x2 o;
            o.x = pk(v.x, v.y);
            o.y = pk(v.z, v.w);
            reinterpret_cast<u32x2*>(xb)[i] = o;
        }
        return;
    }
    if (b < XBLKS + WBLKS) {
        int i = (b - XBLKS) * 256 + threadIdx.x;   // one fragment (8 elems)
        const float* s; u16* d; int t; int rows;
        if (i < WTRIP1)            { s = w1l; d = w1lf; t = i;                 rows = HID_DIM; }
        else if (i < 2*WTRIP1)     { s = w1r; d = w1rf; t = i - WTRIP1;        rows = HID_DIM; }
        else if (i < 2*WTRIP1+WTRIP2)   { s = w2l; d = w2lf; t = i - 2*WTRIP1; rows = OUT_DIM; }
        else if (i < 2*WTRIP1+2*WTRIP2) { s = w2r; d = w2rf; t = i - 2*WTRIP1-WTRIP2; rows = OUT_DIM; }
        else return;
        int lane = t & 63;
        int ks = (t >> 6) & 3;
        int ct = t >> 8;
        int row = ct * 16 + (lane & 15);
        int col = ks * 32 + (lane >> 4) * 8;
        u32x4 o;
        if (row < rows) {
            const float* sp = s + row * 128 + col;
            float4v v0 = *reinterpret_cast<const float4v*>(sp);
            float4v v1 = *reinterpret_cast<const float4v*>(sp + 4);
            o.x = pk(v0.x, v0.y); o.y = pk(v0.z, v0.w);
            o.z = pk(v1.x, v1.y); o.w = pk(v1.z, v1.w);
        } else { o.x = 0; o.y = 0; o.z = 0; o.w = 0; }
        reinterpret_cast<u32x4*>(d)[t] = o;
        return;
    }
    // histogram part
    int t = threadIdx.x;
    for (int i = t; i < NBUCK; i += 256) cnt[i] = 0;
    __syncthreads();
    int base = (b - XBLKS - WBLKS) * CHUNK;
    int n = min(CHUNK, N_EDGES - base);
    for (int i = t; i < n; i += 256)
        atomicAdd(&cnt[idx[N_EDGES + base + i] >> BSHIFT], 1);
    __syncthreads();
    for (int i = t; i < NBUCK; i += 256)
        if (cnt[i]) atomicAdd(&bucket_size[i], cnt[i]);
}

// ---- CSR build: radix partition by dst bucket -------------------------------

__global__ __launch_bounds__(256) void k_bscan(const int* __restrict__ bucket_size,
                                               int* __restrict__ bucket_base,
                                               int* __restrict__ bucket_cur) {
    __shared__ int sa[256], sb[256];
    int t = threadIdx.x;
    int v = (t < NBUCK) ? bucket_size[t] : 0;
    sa[t] = v;
    __syncthreads();
    int *s = sa, *d = sb;
    for (int dd = 1; dd < 256; dd <<= 1) {
        d[t] = s[t] + ((t >= dd) ? s[t - dd] : 0);
        __syncthreads();
        int* tm = s; s = d; d = tm;
    }
    if (t < NBUCK) {
        int base = s[t] - v;   // exclusive prefix
        bucket_base[t] = base;
        bucket_cur[t] = base;
    }
}

__global__ __launch_bounds__(1024) void k_bscatter(const int* __restrict__ idx,
                                                   int* __restrict__ bucket_cur,
                                                   u64* __restrict__ rec) {
    __shared__ int cnt[NBUCK], lofs[NBUCK], gbase[NBUCK], cnt2[NBUCK];
    __shared__ int sa[256], sb[256];
    __shared__ u64 lrec[CHUNK];
    int t = threadIdx.x;
    int nt = blockDim.x;
    for (int i = t; i < NBUCK; i += nt) { cnt[i] = 0; cnt2[i] = 0; }
    __syncthreads();
    int base = blockIdx.x * CHUNK;
    int n = min(CHUNK, N_EDGES - base);
    for (int i = t; i < n; i += nt)
        atomicAdd(&cnt[idx[N_EDGES + base + i] >> BSHIFT], 1);
    __syncthreads();
    if (t < 256) {
        int v = (t < NBUCK) ? cnt[t] : 0;
        sa[t] = v;
    }
    __syncthreads();
    int *s = sa, *d = sb;
    for (int dd = 1; dd < 256; dd <<= 1) {
        if (t < 256) d[t] = s[t] + ((t >= dd) ? s[t - dd] : 0);
        __syncthreads();
        int* tm = s; s = d; d = tm;
    }
    if (t < NBUCK) {
        int v = cnt[t];
        lofs[t] = s[t] - v;
        gbase[t] = v ? atomicAdd(&bucket_cur[t], v) : 0;
    }
    __syncthreads();
    for (int i = t; i < n; i += nt) {
        int srcv = idx[base + i];
        int dstv = idx[N_EDGES + base + i];
        int b = dstv >> BSHIFT;
        int p = lofs[b] + atomicAdd(&cnt2[b], 1);
        lrec[p] = ((u64)(u32)dstv << 32) | (u32)srcv;
    }
    __syncthreads();
    for (int i = t; i < n; i += nt) {
        u64 r = lrec[i];
        int b = ((int)(r >> 32)) >> BSHIFT;
        rec[gbase[b] + (i - lofs[b])] = r;
    }
}

// row_start is N_NODES+1 entries; row_end[n] == row_start[n+1] by construction.
__global__ __launch_bounds__(1024) void k_bfill(const u64* __restrict__ rec,
                                                const int* __restrict__ bucket_base,
                                                const int* __restrict__ bucket_size,
                                                int* __restrict__ row_start,
                                                int* __restrict__ csr) {
    __shared__ int deg[512], cur[512];
    __shared__ int sa[512], sb[512];
    int t = threadIdx.x;
    int nt = blockDim.x;
    int b = blockIdx.x;
    int node0 = b << BSHIFT;
    int nn = min(512, N_NODES - node0);
    int ebase = bucket_base[b];
    int esz = bucket_size[b];
    for (int i = t; i < 512; i += nt) deg[i] = 0;
    __syncthreads();
    for (int i = t; i < esz; i += nt)
        atomicAdd(&deg[((int)(rec[ebase + i] >> 32)) & 511], 1);
    __syncthreads();
    for (int i = t; i < 512; i += nt) sa[i] = deg[i];
    __syncthreads();
    int *s = sa, *d = sb;
    for (int dd = 1; dd < 512; dd <<= 1) {
        for (int i = t; i < 512; i += nt) d[i] = s[i] + ((i >= dd) ? s[i - dd] : 0);
        __syncthreads();
        int* tm = s; s = d; d = tm;
    }
    for (int i = t; i < 512; i += nt) {
        int excl = s[i] - deg[i];
        cur[i] = excl;
        if (i < nn) row_start[node0 + i] = ebase + excl;
    }
    if (b == NBUCK - 1 && t == 0) row_start[N_NODES] = N_EDGES;
    __syncthreads();
    for (int i = t; i < esz; i += nt) {
        u64 r = rec[ebase + i];
        int dl = ((int)(r >> 32)) & 511;
        int p = atomicAdd(&cur[dl], 1);
        csr[ebase + p] = (int)(r & 0xffffffffu);
    }
}

// ---- Mean aggregation: one wave per dst node --------------------------------
// Edge-paired gathers: lanes split 32/32, 8B/lane => one instr fetches 512B
// spanning two source rows. 8 edges/iter; indices software-pipelined.

__global__ void k_agg(const u16* __restrict__ feat,
                      const int* __restrict__ csr,
                      const int* __restrict__ row_start,
                      u16* __restrict__ agg) {
    int n = blockIdx.x * 4 + (threadIdx.x >> 6);
    int lane = threadIdx.x & 63;
    if (n >= N_NODES) return;
    int s = row_start[n];
    int e = row_start[n + 1];
    int half = lane >> 5;     // which edge of the pair
    int li = lane & 31;       // 8B chunk within row (dims 4li..4li+3)
    const u32x2* fp = reinterpret_cast<const u32x2*>(feat);   // 32 granules/row
    float a0 = 0.f, a1 = 0.f, a2 = 0.f, a3 = 0.f;
    int p = s;
    int i0 = 0, i1 = 0, i2 = 0, i3 = 0;
    if (p + 8 <= e) {
        i0 = csr[p + half];     i1 = csr[p + 2 + half];
        i2 = csr[p + 4 + half]; i3 = csr[p + 6 + half];
    }
    while (p + 8 <= e) {
        u32x2 v0 = fp[i0 * 32 + li];
        u32x2 v1 = fp[i1 * 32 + li];
        u32x2 v2 = fp[i2 * 32 + li];
        u32x2 v3 = fp[i3 * 32 + li];
        p += 8;
        if (p + 8 <= e) {       // prefetch next indices during gather latency
            i0 = csr[p + half];     i1 = csr[p + 2 + half];
            i2 = csr[p + 4 + half]; i3 = csr[p + 6 + half];
        }
        a0 += bflo(v0.x) + bflo(v1.x) + bflo(v2.x) + bflo(v3.x);
        a1 += bfhi(v0.x) + bfhi(v1.x) + bfhi(v2.x) + bfhi(v3.x);
        a2 += bflo(v0.y) + bflo(v1.y) + bflo(v2.y) + bflo(v3.y);
        a3 += bfhi(v0.y) + bfhi(v1.y) + bfhi(v2.y) + bfhi(v3.y);
    }
    for (; p + 2 <= e; p += 2) {
        int i = csr[p + half];
        u32x2 v = fp[i * 32 + li];
        a0 += bflo(v.x); a1 += bfhi(v.x);
        a2 += bflo(v.y); a3 += bfhi(v.y);
    }
    if (p < e && half == 0) {   // single leftover edge: lo-half lanes only
        int i = csr[p];
        u32x2 v = fp[i * 32 + li];
        a0 += bflo(v.x); a1 += bfhi(v.x);
        a2 += bflo(v.y); a3 += bfhi(v.y);
    }
    a0 += __shfl_xor(a0, 32);
    a1 += __shfl_xor(a1, 32);
    a2 += __shfl_xor(a2, 32);
    a3 += __shfl_xor(a3, 32);
    if (half == 0) {
        float sc = 1.0f / (float)max(e - s, 1);
        u32x2 o;
        o.x = pk(a0 * sc, a1 * sc);
        o.y = pk(a2 * sc, a3 * sc);
        reinterpret_cast<u32x2*>(agg)[n * 32 + li] = o;
    }
}

// ---- Dense layer 1: h = relu(normalize(agg@W1l^T + b1 + x@W1r^T)) ----------
// W pre-swizzled to fragment-linear; staged to LDS once per block; B-frags via
// conflict-free ds_read_b128. A-frags issued before the staging barrier.

__global__ __launch_bounds__(256) void k_dense1(
    const u16* __restrict__ agg, const u16* __restrict__ x,
    const u16* __restrict__ W1lf, const u16* __restrict__ W1rf,
    const float* __restrict__ b1, u16* __restrict__ h) {
    __shared__ short8 wsh[2][WTRIP1];       // 64 KB
    int t = threadIdx.x;
    int wave = t >> 6;
    int lane = t & 63;
    int nb = blockIdx.x * 64 + wave * 16;
    int q = lane >> 4;
    int m = lane & 15;
    int arow = nb + m;
    if (arow >= N_NODES) arow = N_NODES - 1;   // clamp loads; stores are guarded

    // A-frags first: global latency hides under staging + barrier
    short8 afr[8];
    #pragma unroll
    for (int ks = 0; ks < 4; ++ks) {
        afr[ks]     = *reinterpret_cast<const short8*>(agg + arow * 128 + ks * 32 + q * 8);
        afr[4 + ks] = *reinterpret_cast<const short8*>(x   + arow * 128 + ks * 32 + q * 8);
    }
    // stage both W matrices (fragment-linear => linear copy, conflict-free)
    const short8* g0 = reinterpret_cast<const short8*>(W1lf);
    const short8* g1 = reinterpret_cast<const short8*>(W1rf);
    #pragma unroll
    for (int k = 0; k < 8; ++k) {
        wsh[0][t + k * 256] = g0[t + k * 256];
        wsh[1][t + k * 256] = g1[t + k * 256];
    }
    __syncthreads();

    float4v acc[8];
    #pragma unroll
    for (int ct = 0; ct < 8; ++ct) acc[ct] = (float4v){0.f, 0.f, 0.f, 0.f};

    #pragma unroll
    for (int half = 0; half < 2; ++half)
        #pragma unroll
        for (int ks = 0; ks < 4; ++ks) {
            short8 a = afr[half * 4 + ks];
            #pragma unroll
            for (int ct = 0; ct < 8; ++ct) {
                short8 b = wsh[half][(ct * 4 + ks) * 64 + lane];
                acc[ct] = __builtin_amdgcn_mfma_f32_16x16x32_bf16(a, b, acc[ct], 0, 0, 0);
            }
        }

    float bias[8];
    #pragma unroll
    for (int ct = 0; ct < 8; ++ct) bias[ct] = b1[ct * 16 + m];

    float nsq[4] = { 0.f, 0.f, 0.f, 0.f };
    #pragma unroll
    for (int ct = 0; ct < 8; ++ct)
        #pragma unroll
        for (int r = 0; r < 4; ++r) {
            float v = acc[ct][r] + bias[ct];
            acc[ct][r] = v;
            nsq[r] += v * v;
        }
    #pragma unroll
    for (int r = 0; r < 4; ++r) {
        float tt = nsq[r];
        tt += __shfl_xor(tt, 1);
        tt += __shfl_xor(tt, 2);
        tt += __shfl_xor(tt, 4);
        tt += __shfl_xor(tt, 8);
        nsq[r] = 1.0f / fmaxf(sqrtf(tt), 1e-12f);
    }
    #pragma unroll
    for (int r = 0; r < 4; ++r) {
        int node = nb + q * 4 + r;
        if (node < N_NODES) {
            #pragma unroll
            for (int ct = 0; ct < 8; ++ct) {
                float v = fmaxf(acc[ct][r] * nsq[r], 0.0f);
                h[node * 128 + ct * 16 + m] = f2bf(v);
            }
        }
    }
}

// ---- Dense layer 2 + log_softmax --------------------------------------------
// Same LDS-staged structure; 3 ct tiles (cols 40..47 zero-padded weights).

__global__ __launch_bounds__(256) void k_dense2(
    const u16* __restrict__ agg, const u16* __restrict__ hfeat,
    const u16* __restrict__ W2lf, const u16* __restrict__ W2rf,
    const float* __restrict__ b2, float* __restrict__ out) {
    __shared__ short8 wsh[2][WTRIP2];       // 24 KB
    int t = threadIdx.x;
    int wave = t >> 6;
    int lane = t & 63;
    int nb = blockIdx.x * 64 + wave * 16;
    int q = lane >> 4;
    int m = lane & 15;
    int arow = nb + m;
    if (arow >= N_NODES) arow = N_NODES - 1;

    short8 afr[8];
    #pragma unroll
    for (int ks = 0; ks < 4; ++ks) {
        afr[ks]     = *reinterpret_cast<const short8*>(agg   + arow * 128 + ks * 32 + q * 8);
        afr[4 + ks] = *reinterpret_cast<const short8*>(hfeat + arow * 128 + ks * 32 + q * 8);
    }
    const short8* g0 = reinterpret_cast<const short8*>(W2lf);
    const short8* g1 = reinterpret_cast<const short8*>(W2rf);
    #pragma unroll
    for (int k = 0; k < 3; ++k) {
        wsh[0][t + k * 256] = g0[t + k * 256];
        wsh[1][t + k * 256] = g1[t + k * 256];
    }
    __syncthreads();

    float4v acc[3];
    #pragma unroll
    for (int ct = 0; ct < 3; ++ct) acc[ct] = (float4v){0.f, 0.f, 0.f, 0.f};

    #pragma unroll
    for (int half = 0; half < 2; ++half)
        #pragma unroll
        for (int ks = 0; ks < 4; ++ks) {
            short8 a = afr[half * 4 + ks];
            #pragma unroll
            for (int ct = 0; ct < 3; ++ct) {
                short8 b = wsh[half][(ct * 4 + ks) * 64 + lane];
                acc[ct] = __builtin_amdgcn_mfma_f32_16x16x32_bf16(a, b, acc[ct], 0, 0, 0);
            }
        }

    float bias[3];
    #pragma unroll
    for (int ct = 0; ct < 3; ++ct) {
        int row = ct * 16 + m;
        bias[ct] = (row < OUT_DIM) ? b2[row] : 0.0f;
    }

    float nsq[4] = { 0.f, 0.f, 0.f, 0.f };
    #pragma unroll
    for (int ct = 0; ct < 3; ++ct)
        #pragma unroll
        for (int r = 0; r < 4; ++r) {
            float v = acc[ct][r] + bias[ct];
            acc[ct][r] = v;
            nsq[r] += v * v;
        }
    #pragma unroll
    for (int r = 0; r < 4; ++r) {
        float tt = nsq[r];
        tt += __shfl_xor(tt, 1);
        tt += __shfl_xor(tt, 2);
        tt += __shfl_xor(tt, 4);
        tt += __shfl_xor(tt, 8);
        nsq[r] = 1.0f / fmaxf(sqrtf(tt), 1e-12f);
    }

    float mv[4] = { 0.f, 0.f, 0.f, 0.f };
    #pragma unroll
    for (int ct = 0; ct < 3; ++ct)
        #pragma unroll
        for (int r = 0; r < 4; ++r) {
            float v = fmaxf(acc[ct][r] * nsq[r], 0.0f);
            acc[ct][r] = v;
            mv[r] = fmaxf(mv[r], v);
        }
    #pragma unroll
    for (int r = 0; r < 4; ++r) {
        float tt = mv[r];
        tt = fmaxf(tt, __shfl_xor(tt, 1));
        tt = fmaxf(tt, __shfl_xor(tt, 2));
        tt = fmaxf(tt, __shfl_xor(tt, 4));
        tt = fmaxf(tt, __shfl_xor(tt, 8));
        mv[r] = tt;
    }

    float se[4] = { 0.f, 0.f, 0.f, 0.f };
    #pragma unroll
    for (int ct = 0; ct < 3; ++ct) {
        bool valid = (ct < 2) || (m < 8);
        #pragma unroll
        for (int r = 0; r < 4; ++r)
            se[r] += valid ? __expf(acc[ct][r] - mv[r]) : 0.0f;
    }
    #pragma unroll
    for (int r = 0; r < 4; ++r) {
        float tt = se[r];
        tt += __shfl_xor(tt, 1);
        tt += __shfl_xor(tt, 2);
        tt += __shfl_xor(tt, 4);
        tt += __shfl_xor(tt, 8);
        se[r] = __logf(tt);
    }

    #pragma unroll
    for (int r = 0; r < 4; ++r) {
        int node = nb + q * 4 + r;
        if (node < N_NODES) {
            #pragma unroll
            for (int ct = 0; ct < 3; ++ct) {
                int col = ct * 16 + m;
                if (col < OUT_DIM)
                    out[node * OUT_DIM + col] = acc[ct][r] - mv[r] - se[r];
            }
        }
    }
}

// ---- launch -----------------------------------------------------------------

extern "C" void kernel_launch(void* const* d_in, const int* in_sizes, int n_in,
                              void* d_out, int out_size, void* d_ws, size_t ws_size,
                              hipStream_t stream) {
    const float* x   = (const float*)d_in[0];
    const int*   idx = (const int*)d_in[1];
    const float* W1l = (const float*)d_in[2];
    const float* b1  = (const float*)d_in[3];
    const float* W1r = (const float*)d_in[4];
    const float* W2l = (const float*)d_in[5];
    const float* b2  = (const float*)d_in[6];
    const float* W2r = (const float*)d_in[7];
    float* out = (float*)d_out;

    char* ws = (char*)d_ws;
    int*   bucket_size = (int*)(ws + 0);        // 784 B (memset 0)
    int*   bucket_base = (int*)(ws + 4096);     // 784 B
    int*   bucket_cur  = (int*)(ws + 8192);     // 784 B
    int*   row_start   = (int*)(ws + 16384);    // (N+1)*4 B
    int*   csr         = (int*)(ws + 1216384);  // 6.4 MB -> ends 7616384
    u16*   xb          = (u16*)(ws + 7616512);  // 25.6 MB bf16(x)
    u16*   agg         = (u16*)(ws + 33216512); // 25.6 MB
    u16*   h           = (u16*)(ws + 58816512); // 25.6 MB
    u64*   rec         = (u64*)(ws + 58816512); // 12.8 MB, ALIASES h (disjoint lifetime)
    u16*   W1lf        = (u16*)(ws + 84416512); // 32768 B (frag-linear)
    u16*   W1rf        = (u16*)(ws + 84449280); // 32768 B
    u16*   W2lf        = (u16*)(ws + 84482048); // 12288 B (frag-linear, 48 rows)
    u16*   W2rf        = (u16*)(ws + 84494336); // 12288 B

    hipMemsetAsync(bucket_size, 0, NBUCK * sizeof(int), stream);

    // conversions (x + swizzled weights) + bucket histogram, one launch
    k_cvtall<<<XBLKS + WBLKS + NCHUNK, 256, 0, stream>>>(
        x, xb, W1l, W1r, W2l, W2r, W1lf, W1rf, W2lf, W2rf, idx, bucket_size);

    // CSR build via radix partition
    k_bscan<<<1, 256, 0, stream>>>(bucket_size, bucket_base, bucket_cur);
    k_bscatter<<<NCHUNK, 1024, 0, stream>>>(idx, bucket_cur, rec);
    k_bfill<<<NBUCK, 1024, 0, stream>>>(rec, bucket_base, bucket_size,
                                        row_start, csr);

    // layer 1
    k_agg<<<N_NODES / 4, 256, 0, stream>>>(xb, csr, row_start, agg);
    k_dense1<<<(N_NODES + 63) / 64, 256, 0, stream>>>(agg, xb, W1lf, W1rf, b1, h);
    // layer 2
    k_agg<<<N_NODES / 4, 256, 0, stream>>>(h, csr, row_start, agg);
    k_dense2<<<(N_NODES + 63) / 64, 256, 0, stream>>>(agg, h, W2lf, W2rf, b2, out);
}

// Round 9
// 300.027 us; speedup vs baseline: 1.3692x; 1.0400x over previous
//
#include <hip/hip_runtime.h>
#include <hip/hip_bf16.h>

#define N_NODES 100000
#define N_EDGES 1600000
#define IN_DIM 128
#define HID_DIM 128
#define OUT_DIM 40

#define BSHIFT 9                 // 512 nodes per bucket
#define NBUCK 196                // ceil(100000/512)
#define CHUNK 4096               // edges per scatter/count block
#define NCHUNK ((N_EDGES + CHUNK - 1) / CHUNK)

typedef __attribute__((ext_vector_type(8))) short short8;   // 8 x bf16 (4 VGPRs)
typedef __attribute__((ext_vector_type(4))) float float4v;  // MFMA C/D + float4 loads
typedef __attribute__((ext_vector_type(2))) unsigned int u32x2;
typedef __attribute__((ext_vector_type(4))) unsigned int u32x4;

typedef unsigned short u16;
typedef unsigned int u32;
typedef unsigned long long u64;

__device__ __forceinline__ float bflo(u32 v) { union { u32 u; float f; } c; c.u = v << 16; return c.f; }
__device__ __forceinline__ float bfhi(u32 v) { union { u32 u; float f; } c; c.u = v & 0xffff0000u; return c.f; }
__device__ __forceinline__ float bf1(u16 v) { union { u32 u; float f; } c; c.u = ((u32)v) << 16; return c.f; }
__device__ __forceinline__ u16 f2bf(float f) {  // RNE
    union { float f; u32 u; } c; c.f = f;
    u32 r = c.u + 0x7fffu + ((c.u >> 16) & 1u);
    return (u16)(r >> 16);
}
__device__ __forceinline__ u32 pk(float lo, float hi) {
    return ((u32)f2bf(hi) << 16) | (u32)f2bf(lo);
}

// ---- fused: x convert + W swizzle-convert + bucket histogram ----------------
// W matrices are converted to MFMA-fragment-linear layout:
//   frag id t = (ct*4+ks)*64 + lane ; element j in [0,8)
//   src: row = ct*16 + (lane&15), col = ks*32 + (lane>>4)*8 + j
//   dst u16 index = t*8 + j  (so a wave's B-frag load = 1 KB contiguous)

#define XBLKS ((N_NODES * IN_DIM / 4 + 255) / 256)
#define WTRIP1 2048              // 8ct*4ks*64lane per W1 matrix
#define WTRIP2 768               // 3ct*4ks*64lane per W2 matrix (48 padded rows)
#define WBLKS 22                 // ceil((2*2048+2*768)/256)

__global__ __launch_bounds__(256) void k_cvtall(
    const float* __restrict__ x, u16* __restrict__ xb,
    const float* __restrict__ w1l, const float* __restrict__ w1r,
    const float* __restrict__ w2l, const float* __restrict__ w2r,
    u16* __restrict__ w1lf, u16* __restrict__ w1rf,
    u16* __restrict__ w2lf, u16* __restrict__ w2rf,
    const int* __restrict__ idx, int* __restrict__ bucket_size) {
    __shared__ int cnt[NBUCK];
    int b = blockIdx.x;
    if (b < XBLKS) {
        int i = b * 256 + threadIdx.x;
        if (i < N_NODES * IN_DIM / 4) {
            float4v v = reinterpret_cast<const float4v*>(x)[i];
            u32x2 o;
            o.x = pk(v.x, v.y);
            o.y = pk(v.z, v.w);
            reinterpret_cast<u32x2*>(xb)[i] = o;
        }
        return;
    }
    if (b < XBLKS + WBLKS) {
        int i = (b - XBLKS) * 256 + threadIdx.x;   // one fragment (8 elems)
        const float* s; u16* d; int t; int rows;
        if (i < WTRIP1)            { s = w1l; d = w1lf; t = i;                 rows = HID_DIM; }
        else if (i < 2*WTRIP1)     { s = w1r; d = w1rf; t = i - WTRIP1;        rows = HID_DIM; }
        else if (i < 2*WTRIP1+WTRIP2)   { s = w2l; d = w2lf; t = i - 2*WTRIP1; rows = OUT_DIM; }
        else if (i < 2*WTRIP1+2*WTRIP2) { s = w2r; d = w2rf; t = i - 2*WTRIP1-WTRIP2; rows = OUT_DIM; }
        else return;
        int lane = t & 63;
        int ks = (t >> 6) & 3;
        int ct = t >> 8;
        int row = ct * 16 + (lane & 15);
        int col = ks * 32 + (lane >> 4) * 8;
        u32x4 o;
        if (row < rows) {
            const float* sp = s + row * 128 + col;
            float4v v0 = *reinterpret_cast<const float4v*>(sp);
            float4v v1 = *reinterpret_cast<const float4v*>(sp + 4);
            o.x = pk(v0.x, v0.y); o.y = pk(v0.z, v0.w);
            o.z = pk(v1.x, v1.y); o.w = pk(v1.z, v1.w);
        } else { o.x = 0; o.y = 0; o.z = 0; o.w = 0; }
        reinterpret_cast<u32x4*>(d)[t] = o;
        return;
    }
    // histogram part
    int t = threadIdx.x;
    for (int i = t; i < NBUCK; i += 256) cnt[i] = 0;
    __syncthreads();
    int base = (b - XBLKS - WBLKS) * CHUNK;
    int n = min(CHUNK, N_EDGES - base);
    for (int i = t; i < n; i += 256)
        atomicAdd(&cnt[idx[N_EDGES + base + i] >> BSHIFT], 1);
    __syncthreads();
    for (int i = t; i < NBUCK; i += 256)
        if (cnt[i]) atomicAdd(&bucket_size[i], cnt[i]);
}

// ---- CSR build: radix partition by dst bucket -------------------------------

__global__ __launch_bounds__(256) void k_bscan(const int* __restrict__ bucket_size,
                                               int* __restrict__ bucket_base,
                                               int* __restrict__ bucket_cur) {
    __shared__ int sa[256], sb[256];
    int t = threadIdx.x;
    int v = (t < NBUCK) ? bucket_size[t] : 0;
    sa[t] = v;
    __syncthreads();
    int *s = sa, *d = sb;
    for (int dd = 1; dd < 256; dd <<= 1) {
        d[t] = s[t] + ((t >= dd) ? s[t - dd] : 0);
        __syncthreads();
        int* tm = s; s = d; d = tm;
    }
    if (t < NBUCK) {
        int base = s[t] - v;   // exclusive prefix
        bucket_base[t] = base;
        bucket_cur[t] = base;
    }
}

// single idx pass; rank within (block,bucket) from the histogram atomic itself;
// direct global writes into per-(block,bucket) reserved segments (~168 B runs).
__global__ __launch_bounds__(1024) void k_bscatter(const int* __restrict__ idx,
                                                   int* __restrict__ bucket_cur,
                                                   u64* __restrict__ rec) {
    __shared__ int cnt[NBUCK], gbase[NBUCK];
    int t = threadIdx.x;
    const int nt = 1024;
    for (int i = t; i < NBUCK; i += nt) cnt[i] = 0;
    __syncthreads();
    int base = blockIdx.x * CHUNK;
    int n = min(CHUNK, N_EDGES - base);
    int eb[4], eq[4];
    u64 er[4];
    #pragma unroll
    for (int k = 0; k < 4; ++k) {
        int i = t + k * nt;
        if (i < n) {
            int srcv = idx[base + i];
            int dstv = idx[N_EDGES + base + i];
            int b = dstv >> BSHIFT;
            eb[k] = b;
            eq[k] = atomicAdd(&cnt[b], 1);
            er[k] = ((u64)(u32)dstv << 32) | (u32)srcv;
        }
    }
    __syncthreads();
    for (int i = t; i < NBUCK; i += nt) {
        int v = cnt[i];
        gbase[i] = v ? atomicAdd(&bucket_cur[i], v) : 0;
    }
    __syncthreads();
    #pragma unroll
    for (int k = 0; k < 4; ++k) {
        int i = t + k * nt;
        if (i < n) rec[gbase[eb[k]] + eq[k]] = er[k];
    }
}

// row_start is N_NODES+1 entries; row_end[n] == row_start[n+1] by construction.
__global__ __launch_bounds__(1024) void k_bfill(const u64* __restrict__ rec,
                                                const int* __restrict__ bucket_base,
                                                const int* __restrict__ bucket_size,
                                                int* __restrict__ row_start,
                                                int* __restrict__ csr) {
    __shared__ int deg[512], cur[512];
    __shared__ int sa[512], sb[512];
    int t = threadIdx.x;
    int nt = blockDim.x;
    int b = blockIdx.x;
    int node0 = b << BSHIFT;
    int nn = min(512, N_NODES - node0);
    int ebase = bucket_base[b];
    int esz = bucket_size[b];
    for (int i = t; i < 512; i += nt) deg[i] = 0;
    __syncthreads();
    for (int i = t; i < esz; i += nt)
        atomicAdd(&deg[((int)(rec[ebase + i] >> 32)) & 511], 1);
    __syncthreads();
    for (int i = t; i < 512; i += nt) sa[i] = deg[i];
    __syncthreads();
    int *s = sa, *d = sb;
    for (int dd = 1; dd < 512; dd <<= 1) {
        for (int i = t; i < 512; i += nt) d[i] = s[i] + ((i >= dd) ? s[i - dd] : 0);
        __syncthreads();
        int* tm = s; s = d; d = tm;
    }
    for (int i = t; i < 512; i += nt) {
        int excl = s[i] - deg[i];
        cur[i] = excl;
        if (i < nn) row_start[node0 + i] = ebase + excl;
    }
    if (b == NBUCK - 1 && t == 0) row_start[N_NODES] = N_EDGES;
    __syncthreads();
    for (int i = t; i < esz; i += nt) {
        u64 r = rec[ebase + i];
        int dl = ((int)(r >> 32)) & 511;
        int p = atomicAdd(&cur[dl], 1);
        csr[ebase + p] = (int)(r & 0xffffffffu);
    }
}

// ---- Mean aggregation (layer 1): one wave per dst node ----------------------
// Edge-paired gathers: lanes split 32/32, 8B/lane => one instr fetches 512B
// spanning two source rows. 8 edges/iter; indices software-pipelined.

__global__ void k_agg(const u16* __restrict__ feat,
                      const int* __restrict__ csr,
                      const int* __restrict__ row_start,
                      u16* __restrict__ agg) {
    int n = blockIdx.x * 4 + (threadIdx.x >> 6);
    int lane = threadIdx.x & 63;
    if (n >= N_NODES) return;
    int s = row_start[n];
    int e = row_start[n + 1];
    int half = lane >> 5;     // which edge of the pair
    int li = lane & 31;       // 8B chunk within row (dims 4li..4li+3)
    const u32x2* fp = reinterpret_cast<const u32x2*>(feat);   // 32 granules/row
    float a0 = 0.f, a1 = 0.f, a2 = 0.f, a3 = 0.f;
    int p = s;
    int i0 = 0, i1 = 0, i2 = 0, i3 = 0;
    if (p + 8 <= e) {
        i0 = csr[p + half];     i1 = csr[p + 2 + half];
        i2 = csr[p + 4 + half]; i3 = csr[p + 6 + half];
    }
    while (p + 8 <= e) {
        u32x2 v0 = fp[i0 * 32 + li];
        u32x2 v1 = fp[i1 * 32 + li];
        u32x2 v2 = fp[i2 * 32 + li];
        u32x2 v3 = fp[i3 * 32 + li];
        p += 8;
        if (p + 8 <= e) {       // prefetch next indices during gather latency
            i0 = csr[p + half];     i1 = csr[p + 2 + half];
            i2 = csr[p + 4 + half]; i3 = csr[p + 6 + half];
        }
        a0 += bflo(v0.x) + bflo(v1.x) + bflo(v2.x) + bflo(v3.x);
        a1 += bfhi(v0.x) + bfhi(v1.x) + bfhi(v2.x) + bfhi(v3.x);
        a2 += bflo(v0.y) + bflo(v1.y) + bflo(v2.y) + bflo(v3.y);
        a3 += bfhi(v0.y) + bfhi(v1.y) + bfhi(v2.y) + bfhi(v3.y);
    }
    for (; p + 2 <= e; p += 2) {
        int i = csr[p + half];
        u32x2 v = fp[i * 32 + li];
        a0 += bflo(v.x); a1 += bfhi(v.x);
        a2 += bflo(v.y); a3 += bfhi(v.y);
    }
    if (p < e && half == 0) {   // single leftover edge: lo-half lanes only
        int i = csr[p];
        u32x2 v = fp[i * 32 + li];
        a0 += bflo(v.x); a1 += bfhi(v.x);
        a2 += bflo(v.y); a3 += bfhi(v.y);
    }
    a0 += __shfl_xor(a0, 32);
    a1 += __shfl_xor(a1, 32);
    a2 += __shfl_xor(a2, 32);
    a3 += __shfl_xor(a3, 32);
    if (half == 0) {
        float sc = 1.0f / (float)max(e - s, 1);
        u32x2 o;
        o.x = pk(a0 * sc, a1 * sc);
        o.y = pk(a2 * sc, a3 * sc);
        reinterpret_cast<u32x2*>(agg)[n * 32 + li] = o;
    }
}

// ---- Dense layer 1: h = relu(normalize(agg@W1l^T + b1 + x@W1r^T)) ----------

__global__ __launch_bounds__(256) void k_dense1(
    const u16* __restrict__ agg, const u16* __restrict__ x,
    const u16* __restrict__ W1lf, const u16* __restrict__ W1rf,
    const float* __restrict__ b1, u16* __restrict__ h) {
    __shared__ short8 wsh[2][WTRIP1];       // 64 KB
    int t = threadIdx.x;
    int wave = t >> 6;
    int lane = t & 63;
    int nb = blockIdx.x * 64 + wave * 16;
    int q = lane >> 4;
    int m = lane & 15;
    int arow = nb + m;
    if (arow >= N_NODES) arow = N_NODES - 1;   // clamp loads; stores are guarded

    short8 afr[8];
    #pragma unroll
    for (int ks = 0; ks < 4; ++ks) {
        afr[ks]     = *reinterpret_cast<const short8*>(agg + arow * 128 + ks * 32 + q * 8);
        afr[4 + ks] = *reinterpret_cast<const short8*>(x   + arow * 128 + ks * 32 + q * 8);
    }
    const short8* g0 = reinterpret_cast<const short8*>(W1lf);
    const short8* g1 = reinterpret_cast<const short8*>(W1rf);
    #pragma unroll
    for (int k = 0; k < 8; ++k) {
        wsh[0][t + k * 256] = g0[t + k * 256];
        wsh[1][t + k * 256] = g1[t + k * 256];
    }
    __syncthreads();

    float4v acc[8];
    #pragma unroll
    for (int ct = 0; ct < 8; ++ct) acc[ct] = (float4v){0.f, 0.f, 0.f, 0.f};

    #pragma unroll
    for (int half = 0; half < 2; ++half)
        #pragma unroll
        for (int ks = 0; ks < 4; ++ks) {
            short8 a = afr[half * 4 + ks];
            #pragma unroll
            for (int ct = 0; ct < 8; ++ct) {
                short8 b = wsh[half][(ct * 4 + ks) * 64 + lane];
                acc[ct] = __builtin_amdgcn_mfma_f32_16x16x32_bf16(a, b, acc[ct], 0, 0, 0);
            }
        }

    float bias[8];
    #pragma unroll
    for (int ct = 0; ct < 8; ++ct) bias[ct] = b1[ct * 16 + m];

    float nsq[4] = { 0.f, 0.f, 0.f, 0.f };
    #pragma unroll
    for (int ct = 0; ct < 8; ++ct)
        #pragma unroll
        for (int r = 0; r < 4; ++r) {
            float v = acc[ct][r] + bias[ct];
            acc[ct][r] = v;
            nsq[r] += v * v;
        }
    #pragma unroll
    for (int r = 0; r < 4; ++r) {
        float tt = nsq[r];
        tt += __shfl_xor(tt, 1);
        tt += __shfl_xor(tt, 2);
        tt += __shfl_xor(tt, 4);
        tt += __shfl_xor(tt, 8);
        nsq[r] = 1.0f / fmaxf(sqrtf(tt), 1e-12f);
    }
    #pragma unroll
    for (int r = 0; r < 4; ++r) {
        int node = nb + q * 4 + r;
        if (node < N_NODES) {
            #pragma unroll
            for (int ct = 0; ct < 8; ++ct) {
                float v = fmaxf(acc[ct][r] * nsq[r], 0.0f);
                h[node * 128 + ct * 16 + m] = f2bf(v);
            }
        }
    }
}

// ---- Dense 2a: y2 = h@W2l^T (rows padded to 64), z = h@W2r^T ----------------
// Linear commutes with mean: aggregating y2 (128 B rows) instead of h (256 B)
// halves the layer-2 gather traffic.

__global__ __launch_bounds__(256) void k_dense2a(
    const u16* __restrict__ h,
    const u16* __restrict__ W2lf, const u16* __restrict__ W2rf,
    u16* __restrict__ y2, u16* __restrict__ z) {
    __shared__ short8 wsh[2][WTRIP2];       // 24 KB
    int t = threadIdx.x;
    int wave = t >> 6;
    int lane = t & 63;
    int nb = blockIdx.x * 64 + wave * 16;
    int q = lane >> 4;
    int m = lane & 15;
    int arow = nb + m;
    if (arow >= N_NODES) arow = N_NODES - 1;

    short8 afr[4];
    #pragma unroll
    for (int ks = 0; ks < 4; ++ks)
        afr[ks] = *reinterpret_cast<const short8*>(h + arow * 128 + ks * 32 + q * 8);
    const short8* g0 = reinterpret_cast<const short8*>(W2lf);
    const short8* g1 = reinterpret_cast<const short8*>(W2rf);
    #pragma unroll
    for (int k = 0; k < 3; ++k) {
        wsh[0][t + k * 256] = g0[t + k * 256];
        wsh[1][t + k * 256] = g1[t + k * 256];
    }
    __syncthreads();

    float4v accl[3], accr[3];
    #pragma unroll
    for (int ct = 0; ct < 3; ++ct) {
        accl[ct] = (float4v){0.f, 0.f, 0.f, 0.f};
        accr[ct] = (float4v){0.f, 0.f, 0.f, 0.f};
    }
    #pragma unroll
    for (int ks = 0; ks < 4; ++ks) {
        short8 a = afr[ks];
        #pragma unroll
        for (int ct = 0; ct < 3; ++ct) {
            accl[ct] = __builtin_amdgcn_mfma_f32_16x16x32_bf16(a, wsh[0][(ct * 4 + ks) * 64 + lane], accl[ct], 0, 0, 0);
            accr[ct] = __builtin_amdgcn_mfma_f32_16x16x32_bf16(a, wsh[1][(ct * 4 + ks) * 64 + lane], accr[ct], 0, 0, 0);
        }
    }
    #pragma unroll
    for (int r = 0; r < 4; ++r) {
        int node = nb + q * 4 + r;
        if (node < N_NODES) {
            #pragma unroll
            for (int ct = 0; ct < 3; ++ct) {
                int col = ct * 16 + m;
                y2[node * 64 + col] = f2bf(accl[ct][r]);
                z[node * 48 + col]  = f2bf(accr[ct][r]);
            }
            y2[node * 64 + 48 + m] = 0;   // zero-pad cols 48..63
        }
    }
}

// ---- Layer-2 aggregation + full fused epilogue ------------------------------
// y2 rows are 64 bf16 = 128 B => 4 edges per 512 B gather instruction
// (16 lanes/row). Group-0 lanes (li<10) end up holding all 40 real cols,
// so bias + L2-norm + relu + log_softmax fuse here; dense2/k_final gone.

__global__ void k_agg2(const u16* __restrict__ y2,
                       const int* __restrict__ csr,
                       const int* __restrict__ row_start,
                       const u16* __restrict__ z,
                       const float* __restrict__ b2,
                       float* __restrict__ out) {
    int n = blockIdx.x * 4 + (threadIdx.x >> 6);
    int lane = threadIdx.x & 63;
    if (n >= N_NODES) return;
    int s = row_start[n];
    int e = row_start[n + 1];
    int g = lane >> 4;        // edge slot 0..3
    int li = lane & 15;       // 8B granule (dims 4li..4li+3)
    const u32x2* fp = reinterpret_cast<const u32x2*>(y2);   // 16 granules/row
    float a0 = 0.f, a1 = 0.f, a2 = 0.f, a3 = 0.f;
    // z + bias for this lane's 4 dims (only li<10 real)
    float zb0 = 0.f, zb1 = 0.f, zb2 = 0.f, zb3 = 0.f;
    if (li < 10) {
        u32x2 zv = *reinterpret_cast<const u32x2*>(z + n * 48 + li * 4);
        float4v bv = *reinterpret_cast<const float4v*>(b2 + li * 4);
        zb0 = bflo(zv.x) + bv.x; zb1 = bfhi(zv.x) + bv.y;
        zb2 = bflo(zv.y) + bv.z; zb3 = bfhi(zv.y) + bv.w;
    }
    int p = s;
    int i0 = 0, i1 = 0;
    if (p + 8 <= e) { i0 = csr[p + g]; i1 = csr[p + 4 + g]; }
    while (p + 8 <= e) {
        u32x2 v0 = fp[i0 * 16 + li];
        u32x2 v1 = fp[i1 * 16 + li];
        p += 8;
        if (p + 8 <= e) { i0 = csr[p + g]; i1 = csr[p + 4 + g]; }
        a0 += bflo(v0.x) + bflo(v1.x);
        a1 += bfhi(v0.x) + bfhi(v1.x);
        a2 += bflo(v0.y) + bflo(v1.y);
        a3 += bfhi(v0.y) + bfhi(v1.y);
    }
    if (p + g < e) {          // masked tail, up to 7 edges
        u32x2 v = fp[csr[p + g] * 16 + li];
        a0 += bflo(v.x); a1 += bfhi(v.x);
        a2 += bflo(v.y); a3 += bfhi(v.y);
    }
    if (p + 4 + g < e) {
        u32x2 v = fp[csr[p + 4 + g] * 16 + li];
        a0 += bflo(v.x); a1 += bfhi(v.x);
        a2 += bflo(v.y); a3 += bfhi(v.y);
    }
    // fold 4 groups -> group 0
    a0 += __shfl_xor(a0, 16); a0 += __shfl_xor(a0, 32);
    a1 += __shfl_xor(a1, 16); a1 += __shfl_xor(a1, 32);
    a2 += __shfl_xor(a2, 16); a2 += __shfl_xor(a2, 32);
    a3 += __shfl_xor(a3, 16); a3 += __shfl_xor(a3, 32);

    // epilogue (computed by all lanes; xor<16 reductions stay in-group;
    // only group 0 stores)
    float sc = 1.0f / (float)max(e - s, 1);
    float v0 = 0.f, v1 = 0.f, v2 = 0.f, v3 = 0.f;
    if (li < 10) {
        v0 = a0 * sc + zb0; v1 = a1 * sc + zb1;
        v2 = a2 * sc + zb2; v3 = a3 * sc + zb3;
    }
    float nsq = v0 * v0 + v1 * v1 + v2 * v2 + v3 * v3;
    nsq += __shfl_xor(nsq, 1);
    nsq += __shfl_xor(nsq, 2);
    nsq += __shfl_xor(nsq, 4);
    nsq += __shfl_xor(nsq, 8);
    float rn = 1.0f / fmaxf(sqrtf(nsq), 1e-12f);
    v0 = fmaxf(v0 * rn, 0.f); v1 = fmaxf(v1 * rn, 0.f);
    v2 = fmaxf(v2 * rn, 0.f); v3 = fmaxf(v3 * rn, 0.f);
    float mv = fmaxf(fmaxf(v0, v1), fmaxf(v2, v3));   // >=0; pads are 0, harmless
    mv = fmaxf(mv, __shfl_xor(mv, 1));
    mv = fmaxf(mv, __shfl_xor(mv, 2));
    mv = fmaxf(mv, __shfl_xor(mv, 4));
    mv = fmaxf(mv, __shfl_xor(mv, 8));
    float se = 0.f;
    if (li < 10)
        se = __expf(v0 - mv) + __expf(v1 - mv) + __expf(v2 - mv) + __expf(v3 - mv);
    se += __shfl_xor(se, 1);
    se += __shfl_xor(se, 2);
    se += __shfl_xor(se, 4);
    se += __shfl_xor(se, 8);
    float lse = __logf(se);
    if (g == 0 && li < 10) {
        float4v o = { v0 - mv - lse, v1 - mv - lse, v2 - mv - lse, v3 - mv - lse };
        *reinterpret_cast<float4v*>(out + n * OUT_DIM + li * 4) = o;
    }
}

// ---- launch -----------------------------------------------------------------

extern "C" void kernel_launch(void* const* d_in, const int* in_sizes, int n_in,
                              void* d_out, int out_size, void* d_ws, size_t ws_size,
                              hipStream_t stream) {
    const float* x   = (const float*)d_in[0];
    const int*   idx = (const int*)d_in[1];
    const float* W1l = (const float*)d_in[2];
    const float* b1  = (const float*)d_in[3];
    const float* W1r = (const float*)d_in[4];
    const float* W2l = (const float*)d_in[5];
    const float* b2  = (const float*)d_in[6];
    const float* W2r = (const float*)d_in[7];
    float* out = (float*)d_out;

    char* ws = (char*)d_ws;
    int*   bucket_size = (int*)(ws + 0);        // 784 B (memset 0)
    int*   bucket_base = (int*)(ws + 4096);     // 784 B
    int*   bucket_cur  = (int*)(ws + 8192);     // 784 B
    int*   row_start   = (int*)(ws + 16384);    // (N+1)*4 B
    int*   csr         = (int*)(ws + 1216384);  // 6.4 MB -> ends 7616384
    u16*   xb          = (u16*)(ws + 7616512);  // 25.6 MB bf16(x)
    u16*   y2          = (u16*)(ws + 7616512);  // 12.8 MB, ALIASES xb (xb dead after dense1)
    u16*   z           = (u16*)(ws + 20416512); // 9.6 MB, in xb region too
    u16*   agg         = (u16*)(ws + 33216512); // 25.6 MB (dead after dense1)
    u16*   h           = (u16*)(ws + 58816512); // 25.6 MB
    u64*   rec         = (u64*)(ws + 58816512); // 12.8 MB, ALIASES h (disjoint lifetime)
    u16*   W1lf        = (u16*)(ws + 84416512); // 32768 B (frag-linear)
    u16*   W1rf        = (u16*)(ws + 84449280); // 32768 B
    u16*   W2lf        = (u16*)(ws + 84482048); // 12288 B (frag-linear, 48 rows)
    u16*   W2rf        = (u16*)(ws + 84494336); // 12288 B

    hipMemsetAsync(bucket_size, 0, NBUCK * sizeof(int), stream);

    // conversions (x + swizzled weights) + bucket histogram, one launch
    k_cvtall<<<XBLKS + WBLKS + NCHUNK, 256, 0, stream>>>(
        x, xb, W1l, W1r, W2l, W2r, W1lf, W1rf, W2lf, W2rf, idx, bucket_size);

    // CSR build via radix partition
    k_bscan<<<1, 256, 0, stream>>>(bucket_size, bucket_base, bucket_cur);
    k_bscatter<<<NCHUNK, 1024, 0, stream>>>(idx, bucket_cur, rec);
    k_bfill<<<NBUCK, 1024, 0, stream>>>(rec, bucket_base, bucket_size,
                                        row_start, csr);

    // layer 1
    k_agg<<<N_NODES / 4, 256, 0, stream>>>(xb, csr, row_start, agg);
    k_dense1<<<(N_NODES + 63) / 64, 256, 0, stream>>>(agg, xb, W1lf, W1rf, b1, h);
    // layer 2: project first (y2 = h@W2l^T, z = h@W2r^T), then aggregate y2,
    // with the full epilogue fused into the aggregation kernel
    k_dense2a<<<(N_NODES + 63) / 64, 256, 0, stream>>>(h, W2lf, W2rf, y2, z);
    k_agg2<<<N_NODES / 4, 256, 0, stream>>>(y2, csr, row_start, z, b2, out);
}

// Round 10
// 284.502 us; speedup vs baseline: 1.4439x; 1.0546x over previous
//
#include <hip/hip_runtime.h>
#include <hip/hip_bf16.h>

#define N_NODES 100000
#define N_EDGES 1600000
#define IN_DIM 128
#define HID_DIM 128
#define OUT_DIM 40

#define BSHIFT 9                 // 512 nodes per bucket
#define NBUCK 196                // ceil(100000/512)
#define CHUNK 4096               // edges per scatter/count block
#define NCHUNK ((N_EDGES + CHUNK - 1) / CHUNK)

typedef __attribute__((ext_vector_type(8))) short short8;   // 8 x bf16 (4 VGPRs)
typedef __attribute__((ext_vector_type(4))) float float4v;  // MFMA C/D + float4 loads
typedef __attribute__((ext_vector_type(2))) float f32x2;
typedef __attribute__((ext_vector_type(2))) unsigned int u32x2;
typedef __attribute__((ext_vector_type(4))) unsigned int u32x4;

typedef unsigned short u16;
typedef unsigned int u32;
typedef unsigned long long u64;

__device__ __forceinline__ float bflo(u32 v) { union { u32 u; float f; } c; c.u = v << 16; return c.f; }
__device__ __forceinline__ float bfhi(u32 v) { union { u32 u; float f; } c; c.u = v & 0xffff0000u; return c.f; }
__device__ __forceinline__ u16 f2bf(float f) {  // RNE
    union { float f; u32 u; } c; c.f = f;
    u32 r = c.u + 0x7fffu + ((c.u >> 16) & 1u);
    return (u16)(r >> 16);
}
__device__ __forceinline__ u32 pk(float lo, float hi) {
    return ((u32)f2bf(hi) << 16) | (u32)f2bf(lo);
}

// manual f32 -> fp8 e4m3fn (OCP), RNE, saturating. Encode-side only (cvt pass).
__device__ __forceinline__ u32 f2fp8(float f) {
    union { float f; u32 u; } c; c.f = f;
    u32 s = (c.u >> 24) & 0x80u;
    u32 a = c.u & 0x7fffffffu;
    u32 code;
    if (a >= 0x3C800000u) {                    // >= 2^-6 : normal range
        if (a > 0x43E00000u) a = 0x43E00000u;  // clamp to 448
        u32 r = a + 0x0007FFFFu + ((a >> 20) & 1u);
        code = (((r >> 23) - 120u) << 3) | ((r >> 20) & 7u);
        if (code > 0x7Eu) code = 0x7Eu;        // saturate (round past 448)
    } else {                                   // subnormal: m = round(|f| * 2^9)
        union { u32 u; float f; } d; d.u = a;
        code = (u32)(int)rintf(d.f * 512.0f);  // 0..8 (8 == 2^-6 == e1m0, ok)
    }
    return s | code;
}

// ---- fused: x convert (bf16 + fp8) + W swizzle-convert + bucket histogram ---
// W matrices are converted to MFMA-fragment-linear layout:
//   frag id t = (ct*4+ks)*64 + lane ; element j in [0,8)
//   src: row = ct*16 + (lane&15), col = ks*32 + (lane>>4)*8 + j
//   dst u16 index = t*8 + j  (so a wave's B-frag load = 1 KB contiguous)

#define XBLKS ((N_NODES * IN_DIM / 4 + 255) / 256)
#define WTRIP1 2048              // 8ct*4ks*64lane per W1 matrix
#define WTRIP2 768               // 3ct*4ks*64lane per W2 matrix (48 padded rows)
#define WBLKS 22                 // ceil((2*2048+2*768)/256)

__global__ __launch_bounds__(256) void k_cvtall(
    const float* __restrict__ x, u16* __restrict__ xb, u32* __restrict__ xb8,
    const float* __restrict__ w1l, const float* __restrict__ w1r,
    const float* __restrict__ w2l, const float* __restrict__ w2r,
    u16* __restrict__ w1lf, u16* __restrict__ w1rf,
    u16* __restrict__ w2lf, u16* __restrict__ w2rf,
    const int* __restrict__ idx, int* __restrict__ bucket_size) {
    __shared__ int cnt[NBUCK];
    int b = blockIdx.x;
    if (b < XBLKS) {
        int i = b * 256 + threadIdx.x;
        if (i < N_NODES * IN_DIM / 4) {
            float4v v = reinterpret_cast<const float4v*>(x)[i];
            u32x2 o;
            o.x = pk(v.x, v.y);
            o.y = pk(v.z, v.w);
            reinterpret_cast<u32x2*>(xb)[i] = o;
            xb8[i] = f2fp8(v.x) | (f2fp8(v.y) << 8) | (f2fp8(v.z) << 16) | (f2fp8(v.w) << 24);
        }
        return;
    }
    if (b < XBLKS + WBLKS) {
        int i = (b - XBLKS) * 256 + threadIdx.x;   // one fragment (8 elems)
        const float* s; u16* d; int t; int rows;
        if (i < WTRIP1)            { s = w1l; d = w1lf; t = i;                 rows = HID_DIM; }
        else if (i < 2*WTRIP1)     { s = w1r; d = w1rf; t = i - WTRIP1;        rows = HID_DIM; }
        else if (i < 2*WTRIP1+WTRIP2)   { s = w2l; d = w2lf; t = i - 2*WTRIP1; rows = OUT_DIM; }
        else if (i < 2*WTRIP1+2*WTRIP2) { s = w2r; d = w2rf; t = i - 2*WTRIP1-WTRIP2; rows = OUT_DIM; }
        else return;
        int lane = t & 63;
        int ks = (t >> 6) & 3;
        int ct = t >> 8;
        int row = ct * 16 + (lane & 15);
        int col = ks * 32 + (lane >> 4) * 8;
        u32x4 o;
        if (row < rows) {
            const float* sp = s + row * 128 + col;
            float4v v0 = *reinterpret_cast<const float4v*>(sp);
            float4v v1 = *reinterpret_cast<const float4v*>(sp + 4);
            o.x = pk(v0.x, v0.y); o.y = pk(v0.z, v0.w);
            o.z = pk(v1.x, v1.y); o.w = pk(v1.z, v1.w);
        } else { o.x = 0; o.y = 0; o.z = 0; o.w = 0; }
        reinterpret_cast<u32x4*>(d)[t] = o;
        return;
    }
    // histogram part
    int t = threadIdx.x;
    for (int i = t; i < NBUCK; i += 256) cnt[i] = 0;
    __syncthreads();
    int base = (b - XBLKS - WBLKS) * CHUNK;
    int n = min(CHUNK, N_EDGES - base);
    for (int i = t; i < n; i += 256)
        atomicAdd(&cnt[idx[N_EDGES + base + i] >> BSHIFT], 1);
    __syncthreads();
    for (int i = t; i < NBUCK; i += 256)
        if (cnt[i]) atomicAdd(&bucket_size[i], cnt[i]);
}

// ---- CSR build: radix partition by dst bucket -------------------------------
// (bucket scan recomputed in-block: no separate k_bscan launch; bucket_cur
// starts at 0 — zeroed by the same memset as bucket_size.)

__global__ __launch_bounds__(1024) void k_bscatter(const int* __restrict__ idx,
                                                   const int* __restrict__ bucket_size,
                                                   int* __restrict__ bucket_cur,
                                                   u64* __restrict__ rec) {
    __shared__ int cnt[NBUCK], gbase[NBUCK];
    __shared__ int sa[256], sb[256];
    int t = threadIdx.x;
    const int nt = 1024;
    for (int i = t; i < NBUCK; i += nt) cnt[i] = 0;
    __syncthreads();
    int base = blockIdx.x * CHUNK;
    int n = min(CHUNK, N_EDGES - base);
    int eb[4], eq[4];
    u64 er[4];
    #pragma unroll
    for (int k = 0; k < 4; ++k) {
        int i = t + k * nt;
        if (i < n) {
            int srcv = idx[base + i];
            int dstv = idx[N_EDGES + base + i];
            int b = dstv >> BSHIFT;
            eb[k] = b;
            eq[k] = atomicAdd(&cnt[b], 1);
            er[k] = ((u64)(u32)dstv << 32) | (u32)srcv;
        }
    }
    // in-block exclusive scan of global bucket_size -> bases
    int myv = 0;
    if (t < 256) {
        myv = (t < NBUCK) ? bucket_size[t] : 0;
        sa[t] = myv;
    }
    __syncthreads();
    int *s = sa, *d = sb;
    for (int dd = 1; dd < 256; dd <<= 1) {
        if (t < 256) d[t] = s[t] + ((t >= dd) ? s[t - dd] : 0);
        __syncthreads();
        int* tm = s; s = d; d = tm;
    }
    if (t < NBUCK) {
        int v = cnt[t];
        gbase[t] = v ? (s[t] - myv) + atomicAdd(&bucket_cur[t], v) : 0;
    }
    __syncthreads();
    #pragma unroll
    for (int k = 0; k < 4; ++k) {
        int i = t + k * nt;
        if (i < n) rec[gbase[eb[k]] + eq[k]] = er[k];
    }
}

// row_start is N_NODES+1 entries; row_end[n] == row_start[n+1] by construction.
__global__ __launch_bounds__(1024) void k_bfill(const u64* __restrict__ rec,
                                                const int* __restrict__ bucket_size,
                                                int* __restrict__ row_start,
                                                int* __restrict__ csr) {
    __shared__ int deg[512], cur[512];
    __shared__ int sa[512], sb[512];
    int t = threadIdx.x;
    int nt = blockDim.x;
    int b = blockIdx.x;
    int node0 = b << BSHIFT;
    int nn = min(512, N_NODES - node0);
    int esz = bucket_size[b];
    // in-block exclusive scan of bucket_size -> this bucket's base
    if (t < 256) sa[t] = (t < NBUCK) ? bucket_size[t] : 0;
    __syncthreads();
    {
        int *s = sa, *d = sb;
        for (int dd = 1; dd < 256; dd <<= 1) {
            if (t < 256) d[t] = s[t] + ((t >= dd) ? s[t - dd] : 0);
            __syncthreads();
            int* tm = s; s = d; d = tm;
        }
        if (t == 0) cur[0] = s[b] - esz;   // stash ebase (8 swaps -> s == sa)
    }
    __syncthreads();
    int ebase = cur[0];
    __syncthreads();
    for (int i = t; i < 512; i += nt) deg[i] = 0;
    __syncthreads();
    for (int i = t; i < esz; i += nt)
        atomicAdd(&deg[((int)(rec[ebase + i] >> 32)) & 511], 1);
    __syncthreads();
    for (int i = t; i < 512; i += nt) sa[i] = deg[i];
    __syncthreads();
    int *s = sa, *d = sb;
    for (int dd = 1; dd < 512; dd <<= 1) {
        for (int i = t; i < 512; i += nt) d[i] = s[i] + ((i >= dd) ? s[i - dd] : 0);
        __syncthreads();
        int* tm = s; s = d; d = tm;
    }
    for (int i = t; i < 512; i += nt) {
        int excl = s[i] - deg[i];
        cur[i] = excl;
        if (i < nn) row_start[node0 + i] = ebase + excl;
    }
    if (b == NBUCK - 1 && t == 0) row_start[N_NODES] = N_EDGES;
    __syncthreads();
    for (int i = t; i < esz; i += nt) {
        u64 r = rec[ebase + i];
        int dl = ((int)(r >> 32)) & 511;
        int p = atomicAdd(&cur[dl], 1);
        csr[ebase + p] = (int)(r & 0xffffffffu);
    }
}

// ---- Mean aggregation (layer 1): fp8 table, one wave per dst node -----------
// Rows are 128 B fp8 => 4 edges per 512 B gather instruction (16 lanes/row,
// 8 dims/lane). Decode via HW v_cvt_pk_f32_fp8 (2 floats/op). Output bf16.

__global__ void k_agg(const u32x2* __restrict__ fp,    // fp8 feat, 16 granules/row
                      const int* __restrict__ csr,
                      const int* __restrict__ row_start,
                      u16* __restrict__ agg) {
    int n = blockIdx.x * 4 + (threadIdx.x >> 6);
    int lane = threadIdx.x & 63;
    if (n >= N_NODES) return;
    int s = row_start[n];
    int e = row_start[n + 1];
    int g = lane >> 4;        // edge slot 0..3
    int li = lane & 15;       // 8B granule = dims 8li..8li+7
    float a0 = 0.f, a1 = 0.f, a2 = 0.f, a3 = 0.f;
    float a4 = 0.f, a5 = 0.f, a6 = 0.f, a7 = 0.f;
#define ACC8(v) do { \
        f32x2 d_; \
        d_ = __builtin_amdgcn_cvt_pk_f32_fp8((v).x, false); a0 += d_.x; a1 += d_.y; \
        d_ = __builtin_amdgcn_cvt_pk_f32_fp8((v).x, true);  a2 += d_.x; a3 += d_.y; \
        d_ = __builtin_amdgcn_cvt_pk_f32_fp8((v).y, false); a4 += d_.x; a5 += d_.y; \
        d_ = __builtin_amdgcn_cvt_pk_f32_fp8((v).y, true);  a6 += d_.x; a7 += d_.y; \
    } while (0)
    int p = s;
    int i0 = 0, i1 = 0;
    if (p + 8 <= e) { i0 = csr[p + g]; i1 = csr[p + 4 + g]; }
    while (p + 8 <= e) {
        u32x2 v0 = fp[i0 * 16 + li];
        u32x2 v1 = fp[i1 * 16 + li];
        p += 8;
        if (p + 8 <= e) { i0 = csr[p + g]; i1 = csr[p + 4 + g]; }
        ACC8(v0);
        ACC8(v1);
    }
    if (p + g < e) { u32x2 v = fp[csr[p + g] * 16 + li]; ACC8(v); }
    if (p + 4 + g < e) { u32x2 v = fp[csr[p + 4 + g] * 16 + li]; ACC8(v); }
#undef ACC8
    // fold 4 edge-slots -> slot 0
    a0 += __shfl_xor(a0, 16); a0 += __shfl_xor(a0, 32);
    a1 += __shfl_xor(a1, 16); a1 += __shfl_xor(a1, 32);
    a2 += __shfl_xor(a2, 16); a2 += __shfl_xor(a2, 32);
    a3 += __shfl_xor(a3, 16); a3 += __shfl_xor(a3, 32);
    a4 += __shfl_xor(a4, 16); a4 += __shfl_xor(a4, 32);
    a5 += __shfl_xor(a5, 16); a5 += __shfl_xor(a5, 32);
    a6 += __shfl_xor(a6, 16); a6 += __shfl_xor(a6, 32);
    a7 += __shfl_xor(a7, 16); a7 += __shfl_xor(a7, 32);
    if (g == 0) {
        float sc = 1.0f / (float)max(e - s, 1);
        u32x4 o;
        o.x = pk(a0 * sc, a1 * sc);
        o.y = pk(a2 * sc, a3 * sc);
        o.z = pk(a4 * sc, a5 * sc);
        o.w = pk(a6 * sc, a7 * sc);
        *reinterpret_cast<u32x4*>(agg + n * 128 + li * 8) = o;
    }
}

// ---- Dense layer 1: h = relu(normalize(agg@W1l^T + b1 + x@W1r^T)) ----------

__global__ __launch_bounds__(256) void k_dense1(
    const u16* __restrict__ agg, const u16* __restrict__ x,
    const u16* __restrict__ W1lf, const u16* __restrict__ W1rf,
    const float* __restrict__ b1, u16* __restrict__ h) {
    __shared__ short8 wsh[2][WTRIP1];       // 64 KB
    int t = threadIdx.x;
    int wave = t >> 6;
    int lane = t & 63;
    int nb = blockIdx.x * 64 + wave * 16;
    int q = lane >> 4;
    int m = lane & 15;
    int arow = nb + m;
    if (arow >= N_NODES) arow = N_NODES - 1;   // clamp loads; stores are guarded

    short8 afr[8];
    #pragma unroll
    for (int ks = 0; ks < 4; ++ks) {
        afr[ks]     = *reinterpret_cast<const short8*>(agg + arow * 128 + ks * 32 + q * 8);
        afr[4 + ks] = *reinterpret_cast<const short8*>(x   + arow * 128 + ks * 32 + q * 8);
    }
    const short8* g0 = reinterpret_cast<const short8*>(W1lf);
    const short8* g1 = reinterpret_cast<const short8*>(W1rf);
    #pragma unroll
    for (int k = 0; k < 8; ++k) {
        wsh[0][t + k * 256] = g0[t + k * 256];
        wsh[1][t + k * 256] = g1[t + k * 256];
    }
    __syncthreads();

    float4v acc[8];
    #pragma unroll
    for (int ct = 0; ct < 8; ++ct) acc[ct] = (float4v){0.f, 0.f, 0.f, 0.f};

    #pragma unroll
    for (int half = 0; half < 2; ++half)
        #pragma unroll
        for (int ks = 0; ks < 4; ++ks) {
            short8 a = afr[half * 4 + ks];
            #pragma unroll
            for (int ct = 0; ct < 8; ++ct) {
                short8 b = wsh[half][(ct * 4 + ks) * 64 + lane];
                acc[ct] = __builtin_amdgcn_mfma_f32_16x16x32_bf16(a, b, acc[ct], 0, 0, 0);
            }
        }

    float bias[8];
    #pragma unroll
    for (int ct = 0; ct < 8; ++ct) bias[ct] = b1[ct * 16 + m];

    float nsq[4] = { 0.f, 0.f, 0.f, 0.f };
    #pragma unroll
    for (int ct = 0; ct < 8; ++ct)
        #pragma unroll
        for (int r = 0; r < 4; ++r) {
            float v = acc[ct][r] + bias[ct];
            acc[ct][r] = v;
            nsq[r] += v * v;
        }
    #pragma unroll
    for (int r = 0; r < 4; ++r) {
        float tt = nsq[r];
        tt += __shfl_xor(tt, 1);
        tt += __shfl_xor(tt, 2);
        tt += __shfl_xor(tt, 4);
        tt += __shfl_xor(tt, 8);
        nsq[r] = 1.0f / fmaxf(sqrtf(tt), 1e-12f);
    }
    #pragma unroll
    for (int r = 0; r < 4; ++r) {
        int node = nb + q * 4 + r;
        if (node < N_NODES) {
            #pragma unroll
            for (int ct = 0; ct < 8; ++ct) {
                float v = fmaxf(acc[ct][r] * nsq[r], 0.0f);
                h[node * 128 + ct * 16 + m] = f2bf(v);
            }
        }
    }
}

// ---- Dense 2a: y2 = h@W2l^T (rows padded to 64), z = h@W2r^T ----------------

__global__ __launch_bounds__(256) void k_dense2a(
    const u16* __restrict__ h,
    const u16* __restrict__ W2lf, const u16* __restrict__ W2rf,
    u16* __restrict__ y2, u16* __restrict__ z) {
    __shared__ short8 wsh[2][WTRIP2];       // 24 KB
    int t = threadIdx.x;
    int wave = t >> 6;
    int lane = t & 63;
    int nb = blockIdx.x * 64 + wave * 16;
    int q = lane >> 4;
    int m = lane & 15;
    int arow = nb + m;
    if (arow >= N_NODES) arow = N_NODES - 1;

    short8 afr[4];
    #pragma unroll
    for (int ks = 0; ks < 4; ++ks)
        afr[ks] = *reinterpret_cast<const short8*>(h + arow * 128 + ks * 32 + q * 8);
    const short8* g0 = reinterpret_cast<const short8*>(W2lf);
    const short8* g1 = reinterpret_cast<const short8*>(W2rf);
    #pragma unroll
    for (int k = 0; k < 3; ++k) {
        wsh[0][t + k * 256] = g0[t + k * 256];
        wsh[1][t + k * 256] = g1[t + k * 256];
    }
    __syncthreads();

    float4v accl[3], accr[3];
    #pragma unroll
    for (int ct = 0; ct < 3; ++ct) {
        accl[ct] = (float4v){0.f, 0.f, 0.f, 0.f};
        accr[ct] = (float4v){0.f, 0.f, 0.f, 0.f};
    }
    #pragma unroll
    for (int ks = 0; ks < 4; ++ks) {
        short8 a = afr[ks];
        #pragma unroll
        for (int ct = 0; ct < 3; ++ct) {
            accl[ct] = __builtin_amdgcn_mfma_f32_16x16x32_bf16(a, wsh[0][(ct * 4 + ks) * 64 + lane], accl[ct], 0, 0, 0);
            accr[ct] = __builtin_amdgcn_mfma_f32_16x16x32_bf16(a, wsh[1][(ct * 4 + ks) * 64 + lane], accr[ct], 0, 0, 0);
        }
    }
    #pragma unroll
    for (int r = 0; r < 4; ++r) {
        int node = nb + q * 4 + r;
        if (node < N_NODES) {
            #pragma unroll
            for (int ct = 0; ct < 3; ++ct) {
                int col = ct * 16 + m;
                y2[node * 64 + col] = f2bf(accl[ct][r]);
                z[node * 48 + col]  = f2bf(accr[ct][r]);
            }
            y2[node * 64 + 48 + m] = 0;   // zero-pad cols 48..63
        }
    }
}

// ---- Layer-2 aggregation + full fused epilogue ------------------------------
// y2 rows are 64 bf16 = 128 B => 4 edges per 512 B gather instruction.

__global__ void k_agg2(const u16* __restrict__ y2,
                       const int* __restrict__ csr,
                       const int* __restrict__ row_start,
                       const u16* __restrict__ z,
                       const float* __restrict__ b2,
                       float* __restrict__ out) {
    int n = blockIdx.x * 4 + (threadIdx.x >> 6);
    int lane = threadIdx.x & 63;
    if (n >= N_NODES) return;
    int s = row_start[n];
    int e = row_start[n + 1];
    int g = lane >> 4;        // edge slot 0..3
    int li = lane & 15;       // 8B granule (dims 4li..4li+3)
    const u32x2* fp = reinterpret_cast<const u32x2*>(y2);   // 16 granules/row
    float a0 = 0.f, a1 = 0.f, a2 = 0.f, a3 = 0.f;
    float zb0 = 0.f, zb1 = 0.f, zb2 = 0.f, zb3 = 0.f;
    if (li < 10) {
        u32x2 zv = *reinterpret_cast<const u32x2*>(z + n * 48 + li * 4);
        float4v bv = *reinterpret_cast<const float4v*>(b2 + li * 4);
        zb0 = bflo(zv.x) + bv.x; zb1 = bfhi(zv.x) + bv.y;
        zb2 = bflo(zv.y) + bv.z; zb3 = bfhi(zv.y) + bv.w;
    }
    int p = s;
    int i0 = 0, i1 = 0;
    if (p + 8 <= e) { i0 = csr[p + g]; i1 = csr[p + 4 + g]; }
    while (p + 8 <= e) {
        u32x2 v0 = fp[i0 * 16 + li];
        u32x2 v1 = fp[i1 * 16 + li];
        p += 8;
        if (p + 8 <= e) { i0 = csr[p + g]; i1 = csr[p + 4 + g]; }
        a0 += bflo(v0.x) + bflo(v1.x);
        a1 += bfhi(v0.x) + bfhi(v1.x);
        a2 += bflo(v0.y) + bflo(v1.y);
        a3 += bfhi(v0.y) + bfhi(v1.y);
    }
    if (p + g < e) {
        u32x2 v = fp[csr[p + g] * 16 + li];
        a0 += bflo(v.x); a1 += bfhi(v.x);
        a2 += bflo(v.y); a3 += bfhi(v.y);
    }
    if (p + 4 + g < e) {
        u32x2 v = fp[csr[p + 4 + g] * 16 + li];
        a0 += bflo(v.x); a1 += bfhi(v.x);
        a2 += bflo(v.y); a3 += bfhi(v.y);
    }
    a0 += __shfl_xor(a0, 16); a0 += __shfl_xor(a0, 32);
    a1 += __shfl_xor(a1, 16); a1 += __shfl_xor(a1, 32);
    a2 += __shfl_xor(a2, 16); a2 += __shfl_xor(a2, 32);
    a3 += __shfl_xor(a3, 16); a3 += __shfl_xor(a3, 32);

    float sc = 1.0f / (float)max(e - s, 1);
    float v0 = 0.f, v1 = 0.f, v2 = 0.f, v3 = 0.f;
    if (li < 10) {
        v0 = a0 * sc + zb0; v1 = a1 * sc + zb1;
        v2 = a2 * sc + zb2; v3 = a3 * sc + zb3;
    }
    float nsq = v0 * v0 + v1 * v1 + v2 * v2 + v3 * v3;
    nsq += __shfl_xor(nsq, 1);
    nsq += __shfl_xor(nsq, 2);
    nsq += __shfl_xor(nsq, 4);
    nsq += __shfl_xor(nsq, 8);
    float rn = 1.0f / fmaxf(sqrtf(nsq), 1e-12f);
    v0 = fmaxf(v0 * rn, 0.f); v1 = fmaxf(v1 * rn, 0.f);
    v2 = fmaxf(v2 * rn, 0.f); v3 = fmaxf(v3 * rn, 0.f);
    float mv = fmaxf(fmaxf(v0, v1), fmaxf(v2, v3));
    mv = fmaxf(mv, __shfl_xor(mv, 1));
    mv = fmaxf(mv, __shfl_xor(mv, 2));
    mv = fmaxf(mv, __shfl_xor(mv, 4));
    mv = fmaxf(mv, __shfl_xor(mv, 8));
    float se = 0.f;
    if (li < 10)
        se = __expf(v0 - mv) + __expf(v1 - mv) + __expf(v2 - mv) + __expf(v3 - mv);
    se += __shfl_xor(se, 1);
    se += __shfl_xor(se, 2);
    se += __shfl_xor(se, 4);
    se += __shfl_xor(se, 8);
    float lse = __logf(se);
    if (g == 0 && li < 10) {
        float4v o = { v0 - mv - lse, v1 - mv - lse, v2 - mv - lse, v3 - mv - lse };
        *reinterpret_cast<float4v*>(out + n * OUT_DIM + li * 4) = o;
    }
}

// ---- launch -----------------------------------------------------------------

extern "C" void kernel_launch(void* const* d_in, const int* in_sizes, int n_in,
                              void* d_out, int out_size, void* d_ws, size_t ws_size,
                              hipStream_t stream) {
    const float* x   = (const float*)d_in[0];
    const int*   idx = (const int*)d_in[1];
    const float* W1l = (const float*)d_in[2];
    const float* b1  = (const float*)d_in[3];
    const float* W1r = (const float*)d_in[4];
    const float* W2l = (const float*)d_in[5];
    const float* b2  = (const float*)d_in[6];
    const float* W2r = (const float*)d_in[7];
    float* out = (float*)d_out;

    char* ws = (char*)d_ws;
    int*   bucket_size = (int*)(ws + 0);        // 784 B   } zeroed together
    int*   bucket_cur  = (int*)(ws + 1024);     // 784 B   }
    int*   row_start   = (int*)(ws + 16384);    // (N+1)*4 B
    int*   csr         = (int*)(ws + 1216384);  // 6.4 MB -> ends 7616384
    u16*   xb          = (u16*)(ws + 7616512);  // 25.6 MB bf16(x)
    u16*   y2          = (u16*)(ws + 7616512);  // 12.8 MB, ALIASES xb (dead after dense1)
    u16*   z           = (u16*)(ws + 20416512); // 9.6 MB, also in xb region
    u16*   agg         = (u16*)(ws + 33216512); // 25.6 MB (dead after dense1)
    u64*   rec         = (u64*)(ws + 58816512); // 12.8 MB (h region 1st half; dead after bfill)
    u32*   xb8         = (u32*)(ws + 71616512); // 12.8 MB fp8(x) (h region 2nd half; dead after agg)
    u16*   h           = (u16*)(ws + 58816512); // 25.6 MB (written by dense1, after rec+xb8 dead)
    u16*   W1lf        = (u16*)(ws + 84416512); // 32768 B (frag-linear)
    u16*   W1rf        = (u16*)(ws + 84449280); // 32768 B
    u16*   W2lf        = (u16*)(ws + 84482048); // 12288 B (frag-linear, 48 rows)
    u16*   W2rf        = (u16*)(ws + 84494336); // 12288 B

    hipMemsetAsync(ws, 0, 1808, stream);   // bucket_size + bucket_cur

    // conversions (x bf16+fp8, swizzled weights) + bucket histogram, one launch
    k_cvtall<<<XBLKS + WBLKS + NCHUNK, 256, 0, stream>>>(
        x, xb, xb8, W1l, W1r, W2l, W2r, W1lf, W1rf, W2lf, W2rf, idx, bucket_size);

    // CSR build via radix partition (scan recomputed in-block)
    k_bscatter<<<NCHUNK, 1024, 0, stream>>>(idx, bucket_size, bucket_cur, rec);
    k_bfill<<<NBUCK, 1024, 0, stream>>>(rec, bucket_size, row_start, csr);

    // layer 1 (fp8 gather table)
    k_agg<<<N_NODES / 4, 256, 0, stream>>>((const u32x2*)xb8, csr, row_start, agg);
    k_dense1<<<(N_NODES + 63) / 64, 256, 0, stream>>>(agg, xb, W1lf, W1rf, b1, h);
    // layer 2: project first, then aggregate y2 with fused epilogue
    k_dense2a<<<(N_NODES + 63) / 64, 256, 0, stream>>>(h, W2lf, W2rf, y2, z);
    k_agg2<<<N_NODES / 4, 256, 0, stream>>>(y2, csr, row_start, z, b2, out);
}

// Round 11
// 281.008 us; speedup vs baseline: 1.4618x; 1.0124x over previous
//
#include <hip/hip_runtime.h>
#include <hip/hip_bf16.h>

#define N_NODES 100000
#define N_EDGES 1600000
#define IN_DIM 128
#define HID_DIM 128
#define OUT_DIM 40

#define BSHIFT 9                 // 512 nodes per bucket
#define NBUCK 196                // ceil(100000/512)
#define CHUNK 4096               // edges per scatter/count block
#define NCHUNK ((N_EDGES + CHUNK - 1) / CHUNK)

typedef __attribute__((ext_vector_type(8))) short short8;   // 8 x bf16 (4 VGPRs)
typedef __attribute__((ext_vector_type(4))) float float4v;  // MFMA C/D + float4 loads
typedef __attribute__((ext_vector_type(2))) float f32x2;
typedef __attribute__((ext_vector_type(2))) unsigned int u32x2;
typedef __attribute__((ext_vector_type(4))) unsigned int u32x4;

typedef unsigned char u8;
typedef unsigned short u16;
typedef unsigned int u32;
typedef unsigned long long u64;

__device__ __forceinline__ float bflo(u32 v) { union { u32 u; float f; } c; c.u = v << 16; return c.f; }
__device__ __forceinline__ float bfhi(u32 v) { union { u32 u; float f; } c; c.u = v & 0xffff0000u; return c.f; }
__device__ __forceinline__ u16 f2bf(float f) {  // RNE
    union { float f; u32 u; } c; c.f = f;
    u32 r = c.u + 0x7fffu + ((c.u >> 16) & 1u);
    return (u16)(r >> 16);
}
__device__ __forceinline__ u32 pk(float lo, float hi) {
    return ((u32)f2bf(hi) << 16) | (u32)f2bf(lo);
}

// manual f32 -> fp8 e4m3fn (OCP), RNE, saturating. Encode-side only.
__device__ __forceinline__ u32 f2fp8(float f) {
    union { float f; u32 u; } c; c.f = f;
    u32 s = (c.u >> 24) & 0x80u;
    u32 a = c.u & 0x7fffffffu;
    u32 code;
    if (a >= 0x3C800000u) {                    // >= 2^-6 : normal range
        if (a > 0x43E00000u) a = 0x43E00000u;  // clamp to 448
        u32 r = a + 0x0007FFFFu + ((a >> 20) & 1u);
        code = (((r >> 23) - 120u) << 3) | ((r >> 20) & 7u);
        if (code > 0x7Eu) code = 0x7Eu;
    } else {                                   // subnormal
        union { u32 u; float f; } d; d.u = a;
        code = (u32)(int)rintf(d.f * 512.0f);
    }
    return s | code;
}

// ---- fused: x convert (bf16 + fp8) + W swizzle-convert + bucket histogram ---

#define XBLKS ((N_NODES * IN_DIM / 4 + 255) / 256)
#define WTRIP1 2048              // 8ct*4ks*64lane per W1 matrix
#define WTRIP2 768               // 3ct*4ks*64lane per W2 matrix (48 padded rows)
#define WBLKS 22                 // ceil((2*2048+2*768)/256)

__global__ __launch_bounds__(256) void k_cvtall(
    const float* __restrict__ x, u16* __restrict__ xb, u32* __restrict__ xb8,
    const float* __restrict__ w1l, const float* __restrict__ w1r,
    const float* __restrict__ w2l, const float* __restrict__ w2r,
    u16* __restrict__ w1lf, u16* __restrict__ w1rf,
    u16* __restrict__ w2lf, u16* __restrict__ w2rf,
    const int* __restrict__ idx, int* __restrict__ bucket_size) {
    __shared__ int cnt[NBUCK];
    int b = blockIdx.x;
    if (b < XBLKS) {
        int i = b * 256 + threadIdx.x;
        if (i < N_NODES * IN_DIM / 4) {
            float4v v = reinterpret_cast<const float4v*>(x)[i];
            u32x2 o;
            o.x = pk(v.x, v.y);
            o.y = pk(v.z, v.w);
            reinterpret_cast<u32x2*>(xb)[i] = o;
            xb8[i] = f2fp8(v.x) | (f2fp8(v.y) << 8) | (f2fp8(v.z) << 16) | (f2fp8(v.w) << 24);
        }
        return;
    }
    if (b < XBLKS + WBLKS) {
        int i = (b - XBLKS) * 256 + threadIdx.x;   // one fragment (8 elems)
        const float* s; u16* d; int t; int rows;
        if (i < WTRIP1)            { s = w1l; d = w1lf; t = i;                 rows = HID_DIM; }
        else if (i < 2*WTRIP1)     { s = w1r; d = w1rf; t = i - WTRIP1;        rows = HID_DIM; }
        else if (i < 2*WTRIP1+WTRIP2)   { s = w2l; d = w2lf; t = i - 2*WTRIP1; rows = OUT_DIM; }
        else if (i < 2*WTRIP1+2*WTRIP2) { s = w2r; d = w2rf; t = i - 2*WTRIP1-WTRIP2; rows = OUT_DIM; }
        else return;
        int lane = t & 63;
        int ks = (t >> 6) & 3;
        int ct = t >> 8;
        int row = ct * 16 + (lane & 15);
        int col = ks * 32 + (lane >> 4) * 8;
        u32x4 o;
        if (row < rows) {
            const float* sp = s + row * 128 + col;
            float4v v0 = *reinterpret_cast<const float4v*>(sp);
            float4v v1 = *reinterpret_cast<const float4v*>(sp + 4);
            o.x = pk(v0.x, v0.y); o.y = pk(v0.z, v0.w);
            o.z = pk(v1.x, v1.y); o.w = pk(v1.z, v1.w);
        } else { o.x = 0; o.y = 0; o.z = 0; o.w = 0; }
        reinterpret_cast<u32x4*>(d)[t] = o;
        return;
    }
    // histogram part
    int t = threadIdx.x;
    for (int i = t; i < NBUCK; i += 256) cnt[i] = 0;
    __syncthreads();
    int base = (b - XBLKS - WBLKS) * CHUNK;
    int n = min(CHUNK, N_EDGES - base);
    for (int i = t; i < n; i += 256)
        atomicAdd(&cnt[idx[N_EDGES + base + i] >> BSHIFT], 1);
    __syncthreads();
    for (int i = t; i < NBUCK; i += 256)
        if (cnt[i]) atomicAdd(&bucket_size[i], cnt[i]);
}

// ---- CSR build: radix partition by dst bucket -------------------------------

__global__ __launch_bounds__(1024) void k_bscatter(const int* __restrict__ idx,
                                                   const int* __restrict__ bucket_size,
                                                   int* __restrict__ bucket_cur,
                                                   u64* __restrict__ rec) {
    __shared__ int cnt[NBUCK], gbase[NBUCK];
    __shared__ int sa[256], sb[256];
    int t = threadIdx.x;
    const int nt = 1024;
    for (int i = t; i < NBUCK; i += nt) cnt[i] = 0;
    __syncthreads();
    int base = blockIdx.x * CHUNK;
    int n = min(CHUNK, N_EDGES - base);
    int eb[4], eq[4];
    u64 er[4];
    #pragma unroll
    for (int k = 0; k < 4; ++k) {
        int i = t + k * nt;
        if (i < n) {
            int srcv = idx[base + i];
            int dstv = idx[N_EDGES + base + i];
            int b = dstv >> BSHIFT;
            eb[k] = b;
            eq[k] = atomicAdd(&cnt[b], 1);
            er[k] = ((u64)(u32)dstv << 32) | (u32)srcv;
        }
    }
    int myv = 0;
    if (t < 256) {
        myv = (t < NBUCK) ? bucket_size[t] : 0;
        sa[t] = myv;
    }
    __syncthreads();
    int *s = sa, *d = sb;
    for (int dd = 1; dd < 256; dd <<= 1) {
        if (t < 256) d[t] = s[t] + ((t >= dd) ? s[t - dd] : 0);
        __syncthreads();
        int* tm = s; s = d; d = tm;
    }
    if (t < NBUCK) {
        int v = cnt[t];
        gbase[t] = v ? (s[t] - myv) + atomicAdd(&bucket_cur[t], v) : 0;
    }
    __syncthreads();
    #pragma unroll
    for (int k = 0; k < 4; ++k) {
        int i = t + k * nt;
        if (i < n) rec[gbase[eb[k]] + eq[k]] = er[k];
    }
}

__global__ __launch_bounds__(1024) void k_bfill(const u64* __restrict__ rec,
                                                const int* __restrict__ bucket_size,
                                                int* __restrict__ row_start,
                                                int* __restrict__ csr) {
    __shared__ int deg[512], cur[512];
    __shared__ int sa[512], sb[512];
    int t = threadIdx.x;
    int nt = blockDim.x;
    int b = blockIdx.x;
    int node0 = b << BSHIFT;
    int nn = min(512, N_NODES - node0);
    int esz = bucket_size[b];
    if (t < 256) sa[t] = (t < NBUCK) ? bucket_size[t] : 0;
    __syncthreads();
    {
        int *s = sa, *d = sb;
        for (int dd = 1; dd < 256; dd <<= 1) {
            if (t < 256) d[t] = s[t] + ((t >= dd) ? s[t - dd] : 0);
            __syncthreads();
            int* tm = s; s = d; d = tm;
        }
        if (t == 0) cur[0] = s[b] - esz;
    }
    __syncthreads();
    int ebase = cur[0];
    __syncthreads();
    for (int i = t; i < 512; i += nt) deg[i] = 0;
    __syncthreads();
    for (int i = t; i < esz; i += nt)
        atomicAdd(&deg[((int)(rec[ebase + i] >> 32)) & 511], 1);
    __syncthreads();
    for (int i = t; i < 512; i += nt) sa[i] = deg[i];
    __syncthreads();
    int *s = sa, *d = sb;
    for (int dd = 1; dd < 512; dd <<= 1) {
        for (int i = t; i < 512; i += nt) d[i] = s[i] + ((i >= dd) ? s[i - dd] : 0);
        __syncthreads();
        int* tm = s; s = d; d = tm;
    }
    for (int i = t; i < 512; i += nt) {
        int excl = s[i] - deg[i];
        cur[i] = excl;
        if (i < nn) row_start[node0 + i] = ebase + excl;
    }
    if (b == NBUCK - 1 && t == 0) row_start[N_NODES] = N_EDGES;
    __syncthreads();
    for (int i = t; i < esz; i += nt) {
        u64 r = rec[ebase + i];
        int dl = ((int)(r >> 32)) & 511;
        int p = atomicAdd(&cur[dl], 1);
        csr[ebase + p] = (int)(r & 0xffffffffu);
    }
}

// ---- Mean aggregation (layer 1): fp8 table, one wave per dst node -----------
// 128 B rows, 16 lanes/row, 4 edges/instr. HW fp8 decode + packed f32 adds.

__global__ void k_agg(const u32x2* __restrict__ fp,    // fp8 feat, 16 granules/row
                      const int* __restrict__ csr,
                      const int* __restrict__ row_start,
                      u16* __restrict__ agg) {
    int n = blockIdx.x * 4 + (threadIdx.x >> 6);
    int lane = threadIdx.x & 63;
    if (n >= N_NODES) return;
    int s = row_start[n];
    int e = row_start[n + 1];
    int g = lane >> 4;        // edge slot 0..3
    int li = lane & 15;       // 8B granule = dims 8li..8li+7
    f32x2 ac0 = {0.f, 0.f}, ac1 = {0.f, 0.f}, ac2 = {0.f, 0.f}, ac3 = {0.f, 0.f};
#define ACC8(v) do { \
        ac0 += __builtin_amdgcn_cvt_pk_f32_fp8((v).x, false); \
        ac1 += __builtin_amdgcn_cvt_pk_f32_fp8((v).x, true);  \
        ac2 += __builtin_amdgcn_cvt_pk_f32_fp8((v).y, false); \
        ac3 += __builtin_amdgcn_cvt_pk_f32_fp8((v).y, true);  \
    } while (0)
    int p = s;
    int i0 = 0, i1 = 0;
    if (p + 8 <= e) { i0 = csr[p + g]; i1 = csr[p + 4 + g]; }
    while (p + 8 <= e) {
        u32x2 v0 = fp[i0 * 16 + li];
        u32x2 v1 = fp[i1 * 16 + li];
        p += 8;
        if (p + 8 <= e) { i0 = csr[p + g]; i1 = csr[p + 4 + g]; }
        ACC8(v0);
        ACC8(v1);
    }
    if (p + g < e) { u32x2 v = fp[csr[p + g] * 16 + li]; ACC8(v); }
    if (p + 4 + g < e) { u32x2 v = fp[csr[p + 4 + g] * 16 + li]; ACC8(v); }
#undef ACC8
    float a0 = ac0.x, a1 = ac0.y, a2 = ac1.x, a3 = ac1.y;
    float a4 = ac2.x, a5 = ac2.y, a6 = ac3.x, a7 = ac3.y;
    a0 += __shfl_xor(a0, 16); a0 += __shfl_xor(a0, 32);
    a1 += __shfl_xor(a1, 16); a1 += __shfl_xor(a1, 32);
    a2 += __shfl_xor(a2, 16); a2 += __shfl_xor(a2, 32);
    a3 += __shfl_xor(a3, 16); a3 += __shfl_xor(a3, 32);
    a4 += __shfl_xor(a4, 16); a4 += __shfl_xor(a4, 32);
    a5 += __shfl_xor(a5, 16); a5 += __shfl_xor(a5, 32);
    a6 += __shfl_xor(a6, 16); a6 += __shfl_xor(a6, 32);
    a7 += __shfl_xor(a7, 16); a7 += __shfl_xor(a7, 32);
    if (g == 0) {
        float sc = 1.0f / (float)max(e - s, 1);
        u32x4 o;
        o.x = pk(a0 * sc, a1 * sc);
        o.y = pk(a2 * sc, a3 * sc);
        o.z = pk(a4 * sc, a5 * sc);
        o.w = pk(a6 * sc, a7 * sc);
        *reinterpret_cast<u32x4*>(agg + n * 128 + li * 8) = o;
    }
}

// ---- Dense layer 1: h = relu(normalize(agg@W1l^T + b1 + x@W1r^T)) ----------

__global__ __launch_bounds__(256) void k_dense1(
    const u16* __restrict__ agg, const u16* __restrict__ x,
    const u16* __restrict__ W1lf, const u16* __restrict__ W1rf,
    const float* __restrict__ b1, u16* __restrict__ h) {
    __shared__ short8 wsh[2][WTRIP1];       // 64 KB
    int t = threadIdx.x;
    int wave = t >> 6;
    int lane = t & 63;
    int nb = blockIdx.x * 64 + wave * 16;
    int q = lane >> 4;
    int m = lane & 15;
    int arow = nb + m;
    if (arow >= N_NODES) arow = N_NODES - 1;

    short8 afr[8];
    #pragma unroll
    for (int ks = 0; ks < 4; ++ks) {
        afr[ks]     = *reinterpret_cast<const short8*>(agg + arow * 128 + ks * 32 + q * 8);
        afr[4 + ks] = *reinterpret_cast<const short8*>(x   + arow * 128 + ks * 32 + q * 8);
    }
    const short8* g0 = reinterpret_cast<const short8*>(W1lf);
    const short8* g1 = reinterpret_cast<const short8*>(W1rf);
    #pragma unroll
    for (int k = 0; k < 8; ++k) {
        wsh[0][t + k * 256] = g0[t + k * 256];
        wsh[1][t + k * 256] = g1[t + k * 256];
    }
    __syncthreads();

    float4v acc[8];
    #pragma unroll
    for (int ct = 0; ct < 8; ++ct) acc[ct] = (float4v){0.f, 0.f, 0.f, 0.f};

    #pragma unroll
    for (int half = 0; half < 2; ++half)
        #pragma unroll
        for (int ks = 0; ks < 4; ++ks) {
            short8 a = afr[half * 4 + ks];
            #pragma unroll
            for (int ct = 0; ct < 8; ++ct) {
                short8 b = wsh[half][(ct * 4 + ks) * 64 + lane];
                acc[ct] = __builtin_amdgcn_mfma_f32_16x16x32_bf16(a, b, acc[ct], 0, 0, 0);
            }
        }

    float bias[8];
    #pragma unroll
    for (int ct = 0; ct < 8; ++ct) bias[ct] = b1[ct * 16 + m];

    float nsq[4] = { 0.f, 0.f, 0.f, 0.f };
    #pragma unroll
    for (int ct = 0; ct < 8; ++ct)
        #pragma unroll
        for (int r = 0; r < 4; ++r) {
            float v = acc[ct][r] + bias[ct];
            acc[ct][r] = v;
            nsq[r] += v * v;
        }
    #pragma unroll
    for (int r = 0; r < 4; ++r) {
        float tt = nsq[r];
        tt += __shfl_xor(tt, 1);
        tt += __shfl_xor(tt, 2);
        tt += __shfl_xor(tt, 4);
        tt += __shfl_xor(tt, 8);
        nsq[r] = 1.0f / fmaxf(sqrtf(tt), 1e-12f);
    }
    #pragma unroll
    for (int r = 0; r < 4; ++r) {
        int node = nb + q * 4 + r;
        if (node < N_NODES) {
            #pragma unroll
            for (int ct = 0; ct < 8; ++ct) {
                float v = fmaxf(acc[ct][r] * nsq[r], 0.0f);
                h[node * 128 + ct * 16 + m] = f2bf(v);
            }
        }
    }
}

// ---- Dense 2a: y2 = fp8(64 * h@W2l^T) (64-dim rows), z = bf16(h@W2r^T) ------
// y2 scaled x64 into fp8's healthy range; the 1/64 folds into the mean scale.

__global__ __launch_bounds__(256) void k_dense2a(
    const u16* __restrict__ h,
    const u16* __restrict__ W2lf, const u16* __restrict__ W2rf,
    u8* __restrict__ y2, u16* __restrict__ z) {
    __shared__ short8 wsh[2][WTRIP2];       // 24 KB
    int t = threadIdx.x;
    int wave = t >> 6;
    int lane = t & 63;
    int nb = blockIdx.x * 64 + wave * 16;
    int q = lane >> 4;
    int m = lane & 15;
    int arow = nb + m;
    if (arow >= N_NODES) arow = N_NODES - 1;

    short8 afr[4];
    #pragma unroll
    for (int ks = 0; ks < 4; ++ks)
        afr[ks] = *reinterpret_cast<const short8*>(h + arow * 128 + ks * 32 + q * 8);
    const short8* g0 = reinterpret_cast<const short8*>(W2lf);
    const short8* g1 = reinterpret_cast<const short8*>(W2rf);
    #pragma unroll
    for (int k = 0; k < 3; ++k) {
        wsh[0][t + k * 256] = g0[t + k * 256];
        wsh[1][t + k * 256] = g1[t + k * 256];
    }
    __syncthreads();

    float4v accl[3], accr[3];
    #pragma unroll
    for (int ct = 0; ct < 3; ++ct) {
        accl[ct] = (float4v){0.f, 0.f, 0.f, 0.f};
        accr[ct] = (float4v){0.f, 0.f, 0.f, 0.f};
    }
    #pragma unroll
    for (int ks = 0; ks < 4; ++ks) {
        short8 a = afr[ks];
        #pragma unroll
        for (int ct = 0; ct < 3; ++ct) {
            accl[ct] = __builtin_amdgcn_mfma_f32_16x16x32_bf16(a, wsh[0][(ct * 4 + ks) * 64 + lane], accl[ct], 0, 0, 0);
            accr[ct] = __builtin_amdgcn_mfma_f32_16x16x32_bf16(a, wsh[1][(ct * 4 + ks) * 64 + lane], accr[ct], 0, 0, 0);
        }
    }
    #pragma unroll
    for (int r = 0; r < 4; ++r) {
        int node = nb + q * 4 + r;
        if (node < N_NODES) {
            #pragma unroll
            for (int ct = 0; ct < 3; ++ct) {
                int col = ct * 16 + m;
                y2[node * 64 + col] = (u8)f2fp8(accl[ct][r] * 64.0f);
                z[node * 48 + col]  = f2bf(accr[ct][r]);
            }
            y2[node * 64 + 48 + m] = 0;   // zero-pad dims 48..63
        }
    }
}

// ---- Layer-2 aggregation + full fused epilogue ------------------------------
// fp8 y2 rows = 64 B => 8 edges per 512 B instruction (8 lanes/row, 8 dims/
// lane). 40 = 5 lanes x 8 dims exactly. HW fp8 decode + packed f32 adds.

__global__ void k_agg2(const u32x2* __restrict__ fp,   // fp8 y2, 8 granules/row
                       const int* __restrict__ csr,
                       const int* __restrict__ row_start,
                       const u16* __restrict__ z,
                       const float* __restrict__ b2,
                       float* __restrict__ out) {
    int n = blockIdx.x * 4 + (threadIdx.x >> 6);
    int lane = threadIdx.x & 63;
    if (n >= N_NODES) return;
    int s = row_start[n];
    int e = row_start[n + 1];
    int g = lane >> 3;        // edge slot 0..7
    int li = lane & 7;        // 8B granule = dims 8li..8li+7
    f32x2 ac0 = {0.f, 0.f}, ac1 = {0.f, 0.f}, ac2 = {0.f, 0.f}, ac3 = {0.f, 0.f};
#define ACC8(v) do { \
        ac0 += __builtin_amdgcn_cvt_pk_f32_fp8((v).x, false); \
        ac1 += __builtin_amdgcn_cvt_pk_f32_fp8((v).x, true);  \
        ac2 += __builtin_amdgcn_cvt_pk_f32_fp8((v).y, false); \
        ac3 += __builtin_amdgcn_cvt_pk_f32_fp8((v).y, true);  \
    } while (0)
    int p = s;
    int i0 = 0, i1 = 0;
    if (p + 16 <= e) { i0 = csr[p + g]; i1 = csr[p + 8 + g]; }
    while (p + 16 <= e) {
        u32x2 v0 = fp[i0 * 8 + li];
        u32x2 v1 = fp[i1 * 8 + li];
        p += 16;
        if (p + 16 <= e) { i0 = csr[p + g]; i1 = csr[p + 8 + g]; }
        ACC8(v0);
        ACC8(v1);
    }
    if (p + g < e) { u32x2 v = fp[csr[p + g] * 8 + li]; ACC8(v); }
    if (p + 8 + g < e) { u32x2 v = fp[csr[p + 8 + g] * 8 + li]; ACC8(v); }
#undef ACC8
    float a[8] = { ac0.x, ac0.y, ac1.x, ac1.y, ac2.x, ac2.y, ac3.x, ac3.y };
    #pragma unroll
    for (int j = 0; j < 8; ++j) {
        a[j] += __shfl_xor(a[j], 8);
        a[j] += __shfl_xor(a[j], 16);
        a[j] += __shfl_xor(a[j], 32);
    }

    // epilogue: all lanes compute (xor<8 reductions need all 8 li groups);
    // only g==0 && li<5 stores. sc folds the x64 fp8 scale.
    float sc = 1.0f / (64.0f * (float)max(e - s, 1));
    float v[8];
    if (li < 5) {
        u32x4 zv = *reinterpret_cast<const u32x4*>(z + n * 48 + li * 8);
        float4v bv0 = *reinterpret_cast<const float4v*>(b2 + li * 8);
        float4v bv1 = *reinterpret_cast<const float4v*>(b2 + li * 8 + 4);
        v[0] = a[0] * sc + bflo(zv.x) + bv0.x;
        v[1] = a[1] * sc + bfhi(zv.x) + bv0.y;
        v[2] = a[2] * sc + bflo(zv.y) + bv0.z;
        v[3] = a[3] * sc + bfhi(zv.y) + bv0.w;
        v[4] = a[4] * sc + bflo(zv.z) + bv1.x;
        v[5] = a[5] * sc + bfhi(zv.z) + bv1.y;
        v[6] = a[6] * sc + bflo(zv.w) + bv1.z;
        v[7] = a[7] * sc + bfhi(zv.w) + bv1.w;
    } else {
        #pragma unroll
        for (int j = 0; j < 8; ++j) v[j] = 0.f;
    }
    float nsq = 0.f;
    #pragma unroll
    for (int j = 0; j < 8; ++j) nsq += v[j] * v[j];
    nsq += __shfl_xor(nsq, 1);
    nsq += __shfl_xor(nsq, 2);
    nsq += __shfl_xor(nsq, 4);
    float rn = 1.0f / fmaxf(sqrtf(nsq), 1e-12f);
    float mv = 0.f;
    #pragma unroll
    for (int j = 0; j < 8; ++j) {
        v[j] = fmaxf(v[j] * rn, 0.f);
        mv = fmaxf(mv, v[j]);
    }
    mv = fmaxf(mv, __shfl_xor(mv, 1));
    mv = fmaxf(mv, __shfl_xor(mv, 2));
    mv = fmaxf(mv, __shfl_xor(mv, 4));
    float se = 0.f;
    if (li < 5) {
        #pragma unroll
        for (int j = 0; j < 8; ++j) se += __expf(v[j] - mv);
    }
    se += __shfl_xor(se, 1);
    se += __shfl_xor(se, 2);
    se += __shfl_xor(se, 4);
    float lse = __logf(se);
    if (g == 0 && li < 5) {
        float4v o0 = { v[0] - mv - lse, v[1] - mv - lse, v[2] - mv - lse, v[3] - mv - lse };
        float4v o1 = { v[4] - mv - lse, v[5] - mv - lse, v[6] - mv - lse, v[7] - mv - lse };
        *reinterpret_cast<float4v*>(out + n * OUT_DIM + li * 8) = o0;
        *reinterpret_cast<float4v*>(out + n * OUT_DIM + li * 8 + 4) = o1;
    }
}

// ---- launch -----------------------------------------------------------------

extern "C" void kernel_launch(void* const* d_in, const int* in_sizes, int n_in,
                              void* d_out, int out_size, void* d_ws, size_t ws_size,
                              hipStream_t stream) {
    const float* x   = (const float*)d_in[0];
    const int*   idx = (const int*)d_in[1];
    const float* W1l = (const float*)d_in[2];
    const float* b1  = (const float*)d_in[3];
    const float* W1r = (const float*)d_in[4];
    const float* W2l = (const float*)d_in[5];
    const float* b2  = (const float*)d_in[6];
    const float* W2r = (const float*)d_in[7];
    float* out = (float*)d_out;

    char* ws = (char*)d_ws;
    int*   bucket_size = (int*)(ws + 0);        // 784 B   } zeroed together
    int*   bucket_cur  = (int*)(ws + 1024);     // 784 B   }
    int*   row_start   = (int*)(ws + 16384);    // (N+1)*4 B
    int*   csr         = (int*)(ws + 1216384);  // 6.4 MB -> ends 7616384
    u16*   xb          = (u16*)(ws + 7616512);  // 25.6 MB bf16(x)
    u8*    y2          = (u8*)(ws + 7616512);   // 6.4 MB fp8, ALIASES xb (dead after dense1)
    u16*   z           = (u16*)(ws + 20416512); // 9.6 MB, also in xb region
    u16*   agg         = (u16*)(ws + 33216512); // 25.6 MB (dead after dense1)
    u64*   rec         = (u64*)(ws + 58816512); // 12.8 MB (h region 1st half; dead after bfill)
    u32*   xb8         = (u32*)(ws + 71616512); // 12.8 MB fp8(x) (h region 2nd half; dead after agg)
    u16*   h           = (u16*)(ws + 58816512); // 25.6 MB (written by dense1 after rec+xb8 dead)
    u16*   W1lf        = (u16*)(ws + 84416512); // 32768 B (frag-linear)
    u16*   W1rf        = (u16*)(ws + 84449280); // 32768 B
    u16*   W2lf        = (u16*)(ws + 84482048); // 12288 B (frag-linear, 48 rows)
    u16*   W2rf        = (u16*)(ws + 84494336); // 12288 B

    hipMemsetAsync(ws, 0, 1808, stream);   // bucket_size + bucket_cur

    k_cvtall<<<XBLKS + WBLKS + NCHUNK, 256, 0, stream>>>(
        x, xb, xb8, W1l, W1r, W2l, W2r, W1lf, W1rf, W2lf, W2rf, idx, bucket_size);

    k_bscatter<<<NCHUNK, 1024, 0, stream>>>(idx, bucket_size, bucket_cur, rec);
    k_bfill<<<NBUCK, 1024, 0, stream>>>(rec, bucket_size, row_start, csr);

    // layer 1 (fp8 gather table)
    k_agg<<<N_NODES / 4, 256, 0, stream>>>((const u32x2*)xb8, csr, row_start, agg);
    k_dense1<<<(N_NODES + 63) / 64, 256, 0, stream>>>(agg, xb, W1lf, W1rf, b1, h);
    // layer 2: project to fp8 y2 + bf16 z, then aggregate with fused epilogue
    k_dense2a<<<(N_NODES + 63) / 64, 256, 0, stream>>>(h, W2lf, W2rf, y2, z);
    k_agg2<<<N_NODES / 4, 256, 0, stream>>>((const u32x2*)y2, csr, row_start, z, b2, out);
}